// Round 2
// baseline (4552.613 us; speedup 1.0000x reference)
//
#include <hip/hip_runtime.h>
#include <hip/hip_bf16.h>

#define WB 32
#define WNPB 2048
#define WN 65536
#define WH 768
#define WHEADS 8
#define WDH 96
#define WE 1048576
#define WH3 2304
#define SCALE_QK 0.10206207261596577f

__device__ __forceinline__ float wave_sum64(float v){
  #pragma unroll
  for(int o=32;o;o>>=1) v += __shfl_xor(v,o,64);
  return v;
}
__device__ __forceinline__ float block_sum256(float v, float* red){
  v = wave_sum64(v);
  __syncthreads();
  if((threadIdx.x&63)==0) red[threadIdx.x>>6]=v;
  __syncthreads();
  return red[0]+red[1]+red[2]+red[3];
}
__device__ __forceinline__ float block_max256(float v, float* red){
  #pragma unroll
  for(int o=32;o;o>>=1) v = fmaxf(v,__shfl_xor(v,o,64));
  __syncthreads();
  if((threadIdx.x&63)==0) red[threadIdx.x>>6]=v;
  __syncthreads();
  return fmaxf(fmaxf(red[0],red[1]),fmaxf(red[2],red[3]));
}

// ---------------- init: zero accumulators, first_edge = E ----------------
__global__ __launch_bounds__(256) void k_init(float* wnf, float* meannf,
                                              int* firstedge, int* cntb){
  int t = blockIdx.x*256+threadIdx.x;
  if(t < WB*WHEADS*WH) wnf[t]=0.f;
  if(t < WB*WH) meannf[t]=0.f;
  if(t < WN) firstedge[t]=WE;
  if(t < WB) cntb[t]=0;
}

// ---------------- generic 32-row GEMM: C[b][j]=sum_i A..*W(i,j)+bias ------
// trans: W[j][i]; headmode: A row = wnf[b][j/96][:]; cntb: prescale 1/max(c,1)
// epi: 0 none, 1 relu, 2 LayerNorm(lng,lnb)
__global__ __launch_bounds__(256) void k_rowgemm(
    const float* __restrict__ A, const float* __restrict__ W,
    const float* __restrict__ bias, float* __restrict__ C,
    int K1, int trans, int headmode, const int* __restrict__ cntb,
    int epi, const float* __restrict__ lng, const float* __restrict__ lnb){
  __shared__ float a_lds[WHEADS*WH];
  __shared__ float red[4];
  int b = blockIdx.x, t = threadIdx.x;
  int alen = headmode ? WHEADS*WH : K1;
  const float* Ar = A + (size_t)b*alen;
  float alpha = 1.f;
  if(cntb){ int c=cntb[b]; alpha = 1.f/(float)(c>1?c:1); }
  for(int i=t;i<alen;i+=256) a_lds[i]=Ar[i]*alpha;
  __syncthreads();
  float out[3];
  #pragma unroll
  for(int jo=0;jo<3;++jo){
    int j = jo*256+t;
    const float* ap = a_lds + (headmode ? (j/WDH)*WH : 0);
    float acc=0.f;
    if(!trans){
      const float* wp = W + j;
      #pragma unroll 4
      for(int i=0;i<K1;++i) acc += ap[i]*wp[(size_t)i*WH];
    } else {
      const float* wp = W + (size_t)j*K1;
      #pragma unroll 4
      for(int i=0;i<K1;++i) acc += ap[i]*wp[i];
    }
    if(bias) acc += bias[j];
    if(epi==1) acc = fmaxf(acc,0.f);
    out[jo]=acc;
  }
  if(epi==2){
    float s = block_sum256(out[0]+out[1]+out[2], red);
    float m = s*(1.f/(float)WH);
    float d0=out[0]-m,d1=out[1]-m,d2=out[2]-m;
    float v = block_sum256(d0*d0+d1*d1+d2*d2, red)*(1.f/(float)WH);
    float inv = rsqrtf(v+1e-5f);
    #pragma unroll
    for(int jo=0;jo<3;++jo){ int j=jo*256+t;
      C[(size_t)b*WH+j]=(out[jo]-m)*inv*lng[j]+lnb[j]; }
  } else {
    #pragma unroll
    for(int jo=0;jo<3;++jo){ int j=jo*256+t; C[(size_t)b*WH+j]=out[jo]; }
  }
}

// ---------------- qk_vec[b,i,h] = sum_d q[b,h*96+d]*ak_w[i,h*96+d] --------
__global__ __launch_bounds__(256) void k_qkvec(const float* __restrict__ q,
    const float* __restrict__ akw, const float* __restrict__ akb,
    float* __restrict__ qkvec, float* __restrict__ sconst){
  __shared__ float qlds[WH];
  int b=blockIdx.y, ic=blockIdx.x, t=threadIdx.x;
  for(int i=t;i<WH;i+=256) qlds[i]=q[(size_t)b*WH+i];
  __syncthreads();
  int il=t>>3, h=t&7;
  int i=ic*32+il;
  const float* wr = akw + (size_t)i*WH + h*WDH;
  const float* qr = qlds + h*WDH;
  float acc=0.f;
  #pragma unroll 8
  for(int d=0;d<WDH;++d) acc += qr[d]*wr[d];
  qkvec[((size_t)b*WH+i)*WHEADS + h] = acc;
  if(ic==0 && il==0){
    float sc=0.f;
    for(int d=0;d<WDH;++d) sc += qlds[h*WDH+d]*akb[h*WDH+d];
    sconst[b*WHEADS+h]=sc;
  }
}

// ---------------- numer_const[b]=qp2.bn ; qn[b]=max(||qp2||,1e-8) ---------
__global__ __launch_bounds__(256) void k_qmisc(const float* __restrict__ qp2,
    const float* __restrict__ pbn, float* __restrict__ nconst, float* __restrict__ qn){
  __shared__ float red[4];
  int b=blockIdx.x, t=threadIdx.x;
  float s1=0.f,s2=0.f;
  for(int i=t;i<WH;i+=256){ float v=qp2[(size_t)b*WH+i]; s1+=v*pbn[i]; s2+=v*v; }
  s1=block_sum256(s1,red);
  s2=block_sum256(s2,red);
  if(t==0){ nconst[b]=s1; qn[b]=fmaxf(sqrtf(s2),1e-8f); }
}

// ---------------- node pass 1: scores, numer, per-batch nf sums -----------
__global__ __launch_bounds__(256) void k_node1(
    const float* __restrict__ nf, const int* __restrict__ bidx,
    const float* __restrict__ qkvec, const float* __restrict__ wq2,
    const float* __restrict__ sconst, const float* __restrict__ nconst,
    float* __restrict__ s_out, float* __restrict__ numer,
    float* __restrict__ meannf, int* __restrict__ cntb){
  __shared__ float m_lds[4][WH];
  int lane = threadIdx.x&63, w = threadIdx.x>>6;
  int n0 = blockIdx.x*64;
  int b = bidx[n0];
  const float* qkb = qkvec + (size_t)b*WH*WHEADS;
  const float4* wqb4 = (const float4*)(wq2 + (size_t)b*WH);
  float sc[8];
  #pragma unroll
  for(int h=0;h<8;++h) sc[h]=sconst[b*WHEADS+h];
  float ncst = nconst[b];
  float macc[12];
  #pragma unroll
  for(int i=0;i<12;++i) macc[i]=0.f;
  for(int q_=0;q_<16;++q_){
    int n = n0 + w*16 + q_;
    const float4* nfr = (const float4*)(nf + (size_t)n*WH);
    float acc[8]; float anu=0.f;
    #pragma unroll
    for(int h=0;h<8;++h) acc[h]=0.f;
    #pragma unroll
    for(int tt=0;tt<3;++tt){
      int i4 = lane + 64*tt;
      float4 xv = nfr[i4];
      float4 wv = wqb4[i4];
      const float4* qk4 = (const float4*)(qkb + (size_t)i4*32);
      float xs[4]={xv.x,xv.y,xv.z,xv.w};
      float ws[4]={wv.x,wv.y,wv.z,wv.w};
      #pragma unroll
      for(int u=0;u<4;++u){
        float x = xs[u];
        float4 qa = qk4[2*u], qb = qk4[2*u+1];
        acc[0]+=x*qa.x; acc[1]+=x*qa.y; acc[2]+=x*qa.z; acc[3]+=x*qa.w;
        acc[4]+=x*qb.x; acc[5]+=x*qb.y; acc[6]+=x*qb.z; acc[7]+=x*qb.w;
        anu += x*ws[u];
        macc[tt*4+u]+=x;
      }
    }
    #pragma unroll
    for(int h=0;h<8;++h) acc[h]=wave_sum64(acc[h]);
    anu = wave_sum64(anu);
    if(lane==0){
      #pragma unroll
      for(int h=0;h<8;++h) s_out[(size_t)n*8+h] = SCALE_QK*(acc[h]+sc[h]);
      numer[n] = anu + ncst;
    }
  }
  #pragma unroll
  for(int tt=0;tt<3;++tt){
    #pragma unroll
    for(int u=0;u<4;++u) m_lds[w][4*lane+256*tt+u]=macc[tt*4+u];
  }
  __syncthreads();
  for(int i=threadIdx.x;i<WH;i+=256)
    atomicAdd(&meannf[(size_t)b*WH+i],
              m_lds[0][i]+m_lds[1][i]+m_lds[2][i]+m_lds[3][i]);
  if(threadIdx.x==0) atomicAdd(&cntb[b],64);
}

// ---------------- big fp32 GEMM + square-reduce: nn[n]=||nf@wn+bn|| -------
__global__ __launch_bounds__(256) void k_norm(const float* __restrict__ nf,
    const float* __restrict__ wn, const float* __restrict__ bn,
    float* __restrict__ nnout){
  __shared__ float At[32][136];
  __shared__ float Bt[32][128];
  __shared__ float sq[16][128];
  int t=threadIdx.x, tx=t&15, ty=t>>4;
  int r0=blockIdx.x*128;
  float sqr[8];
  #pragma unroll
  for(int i=0;i<8;++i) sqr[i]=0.f;
  for(int ct=0;ct<WH;ct+=128){
    float acc[8][8];
    #pragma unroll
    for(int i=0;i<8;++i){
      #pragma unroll
      for(int j=0;j<8;++j) acc[i][j]=0.f;
    }
    for(int kt=0;kt<WH;kt+=32){
      __syncthreads();
      {
        int row=t>>1, kof=(t&1)*16;
        const float4* src=(const float4*)(nf + (size_t)(r0+row)*WH + kt + kof);
        float4 v0=src[0], v1=src[1], v2=src[2], v3=src[3];
        At[kof+ 0][row]=v0.x; At[kof+ 1][row]=v0.y; At[kof+ 2][row]=v0.z; At[kof+ 3][row]=v0.w;
        At[kof+ 4][row]=v1.x; At[kof+ 5][row]=v1.y; At[kof+ 6][row]=v1.z; At[kof+ 7][row]=v1.w;
        At[kof+ 8][row]=v2.x; At[kof+ 9][row]=v2.y; At[kof+10][row]=v2.z; At[kof+11][row]=v2.w;
        At[kof+12][row]=v3.x; At[kof+13][row]=v3.y; At[kof+14][row]=v3.z; At[kof+15][row]=v3.w;
      }
      {
        int k=t>>3, c=(t&7)*16;
        const float4* src=(const float4*)(wn + (size_t)(kt+k)*WH + ct + c);
        float4 b0=src[0], b1=src[1], b2=src[2], b3=src[3];
        float4* d=(float4*)&Bt[k][c];
        d[0]=b0; d[1]=b1; d[2]=b2; d[3]=b3;
      }
      __syncthreads();
      #pragma unroll 4
      for(int kk=0;kk<32;++kk){
        float4 a0=*(const float4*)&At[kk][ty*8];
        float4 a1=*(const float4*)&At[kk][ty*8+4];
        float4 b0=*(const float4*)&Bt[kk][tx*8];
        float4 b1=*(const float4*)&Bt[kk][tx*8+4];
        float av[8]={a0.x,a0.y,a0.z,a0.w,a1.x,a1.y,a1.z,a1.w};
        float bv[8]={b0.x,b0.y,b0.z,b0.w,b1.x,b1.y,b1.z,b1.w};
        #pragma unroll
        for(int i=0;i<8;++i){
          #pragma unroll
          for(int j=0;j<8;++j) acc[i][j] += av[i]*bv[j];
        }
      }
    }
    float bj[8];
    #pragma unroll
    for(int j=0;j<8;++j) bj[j]=bn[ct+tx*8+j];
    #pragma unroll
    for(int i=0;i<8;++i){
      #pragma unroll
      for(int j=0;j<8;++j){ float v=acc[i][j]+bj[j]; sqr[i]+=v*v; }
    }
  }
  __syncthreads();
  #pragma unroll
  for(int i=0;i<8;++i) sq[tx][ty*8+i]=sqr[i];
  __syncthreads();
  for(int r=t;r<128;r+=256){
    float tot=0.f;
    #pragma unroll
    for(int x=0;x<16;++x) tot+=sq[x][r];
    nnout[r0+r]=fmaxf(sqrtf(tot),1e-8f);
  }
}

// ---------------- softmax stats per (b,h) over the batch's 2048 nodes -----
__global__ __launch_bounds__(256) void k_stats(const float* __restrict__ s,
    float* __restrict__ rowmax, float* __restrict__ rowinv){
  __shared__ float red[4];
  int b = blockIdx.x>>3, h = blockIdx.x&7;
  const float* sp = s + (size_t)b*WNPB*8 + h;
  float mx=-3e38f;
  for(int i=threadIdx.x;i<WNPB;i+=256) mx=fmaxf(mx, sp[(size_t)i*8]);
  mx = block_max256(mx, red);
  float se=0.f;
  for(int i=threadIdx.x;i<WNPB;i+=256) se += __expf(sp[(size_t)i*8]-mx);
  se = block_sum256(se, red);
  if(threadIdx.x==0){ rowmax[blockIdx.x]=mx; rowinv[blockIdx.x]=1.f/se; }
}

// ---------------- node pass 2: wnf[b,h,:] += softmax(s)[n,h]*nf[n,:] ------
__global__ __launch_bounds__(256) void k_node2(
    const float* __restrict__ nf, const float* __restrict__ s,
    const float* __restrict__ rowmax, const float* __restrict__ rowinv,
    float* __restrict__ wnf){
  __shared__ float p_lds[256*8];
  int b = blockIdx.x>>3, ch = blockIdx.x&7;
  int t = threadIdx.x;
  int n0 = b*WNPB + ch*256;
  float rm[8], ri[8];
  #pragma unroll
  for(int h=0;h<8;++h){ rm[h]=rowmax[b*8+h]; ri[h]=rowinv[b*8+h]; }
  {
    int n = n0+t;
    #pragma unroll
    for(int h=0;h<8;++h) p_lds[t*8+h] = __expf(s[(size_t)n*8+h]-rm[h])*ri[h];
  }
  __syncthreads();
  float racc[24];
  #pragma unroll
  for(int i=0;i<24;++i) racc[i]=0.f;
  const float* nfb = nf + (size_t)n0*WH;
  for(int m=0;m<256;++m){
    float x0 = nfb[(size_t)m*WH + t];
    float x1 = nfb[(size_t)m*WH + t + 256];
    float x2 = nfb[(size_t)m*WH + t + 512];
    const float* pm = p_lds + m*8;
    #pragma unroll
    for(int h=0;h<8;++h){
      float p = pm[h];
      racc[h*3+0] += p*x0; racc[h*3+1] += p*x1; racc[h*3+2] += p*x2;
    }
  }
  float* wb = wnf + (size_t)b*WHEADS*WH;
  #pragma unroll
  for(int h=0;h<8;++h){
    atomicAdd(&wb[h*WH + t],       racc[h*3+0]);
    atomicAdd(&wb[h*WH + t + 256], racc[h*3+1]);
    atomicAdd(&wb[h*WH + t + 512], racc[h*3+2]);
  }
}

// ---------------- per-batch top-3 cosine sim ------------------------------
__device__ __forceinline__ void top3_insert(float v, int i, float* tv, int* ti){
  if (v>tv[0] || (v==tv[0] && i<ti[0])){
    tv[2]=tv[1]; ti[2]=ti[1]; tv[1]=tv[0]; ti[1]=ti[0]; tv[0]=v; ti[0]=i;
  } else if (v>tv[1] || (v==tv[1] && i<ti[1])){
    tv[2]=tv[1]; ti[2]=ti[1]; tv[1]=v; ti[1]=i;
  } else if (v>tv[2] || (v==tv[2] && i<ti[2])){
    tv[2]=v; ti[2]=i;
  }
}
__global__ __launch_bounds__(256) void k_top3(const float* __restrict__ numer,
    const float* __restrict__ nrm, const float* __restrict__ qn,
    int* __restrict__ starts){
  __shared__ float sv[256][3];
  __shared__ int   si[256][3];
  int b=blockIdx.x, t=threadIdx.x;
  float qv = qn[b];
  float tv[3]={-3e38f,-3e38f,-3e38f};
  int   ti[3]={0x7fffffff,0x7fffffff,0x7fffffff};
  for(int u=t;u<WNPB;u+=256){
    int n=b*WNPB+u;
    float v = numer[n]/(qv*nrm[n]);
    top3_insert(v,n,tv,ti);
  }
  sv[t][0]=tv[0];sv[t][1]=tv[1];sv[t][2]=tv[2];
  si[t][0]=ti[0];si[t][1]=ti[1];si[t][2]=ti[2];
  __syncthreads();
  for(int st=128;st;st>>=1){
    if(t<st){
      #pragma unroll
      for(int k=0;k<3;++k) top3_insert(sv[t+st][k], si[t+st][k], tv, ti);
      sv[t][0]=tv[0];sv[t][1]=tv[1];sv[t][2]=tv[2];
      si[t][0]=ti[0];si[t][1]=ti[1];si[t][2]=ti[2];
    }
    __syncthreads();
  }
  if(t<3) starts[b*3+t]=si[0][t];
}

// ---------------- edge scan: first intra edge per src node ----------------
__global__ __launch_bounds__(256) void k_edges(const int* __restrict__ ei,
    const int* __restrict__ bidx, int* __restrict__ firstedge){
  int e = blockIdx.x*256+threadIdx.x;
  if(e<WE){
    int s=ei[e], d=ei[WE+e];
    if(bidx[s]==bidx[d]) atomicMin(&firstedge[s], e);
  }
}

// ---------------- per-batch path features ---------------------------------
__global__ __launch_bounds__(256) void k_path(const int* __restrict__ starts,
    const int* __restrict__ firstedge, const int* __restrict__ dst,
    const float* __restrict__ nf, float* __restrict__ mpaths,
    int* __restrict__ cntpath){
  int b=blockIdx.x;
  int sl[3], nl[3], vl[3]; int cnt=0;
  #pragma unroll
  for(int k=0;k<3;++k){
    int st = starts[b*3+k];
    int fe = firstedge[st];
    int valid = fe<WE;
    sl[k]=st; nl[k]= valid? dst[fe] : 0; vl[k]=valid; cnt+=valid;
  }
  float inv = 1.f/(float)(cnt>1?cnt:1);
  for(int j=threadIdx.x;j<WH;j+=256){
    float acc=0.f;
    #pragma unroll
    for(int k=0;k<3;++k)
      if(vl[k]) acc += 0.5f*(nf[(size_t)sl[k]*WH+j] + nf[(size_t)nl[k]*WH+j]);
    mpaths[(size_t)b*WH+j]=acc*inv;
  }
  if(threadIdx.x==0) cntpath[b]=cnt;
}

// ---------------- select agg vs batch_mean, LayerNorm ---------------------
__global__ __launch_bounds__(256) void k_selln(const float* __restrict__ agg,
    const float* __restrict__ bmean, const int* __restrict__ cntpath,
    const float* __restrict__ g, const float* __restrict__ bb,
    float* __restrict__ out){
  __shared__ float red[4];
  int b=blockIdx.x, t=threadIdx.x;
  const float* src = (cntpath[b]>0? agg : bmean) + (size_t)b*WH;
  float x[3];
  #pragma unroll
  for(int jo=0;jo<3;++jo) x[jo]=src[jo*256+t];
  float s = block_sum256(x[0]+x[1]+x[2], red);
  float m = s*(1.f/768.f);
  float d0=x[0]-m,d1=x[1]-m,d2=x[2]-m;
  float v = block_sum256(d0*d0+d1*d1+d2*d2, red)*(1.f/768.f);
  float inv = rsqrtf(v+1e-5f);
  #pragma unroll
  for(int jo=0;jo<3;++jo){ int j=jo*256+t;
    out[(size_t)b*WH+j]=(x[jo]-m)*inv*g[j]+bb[j]; }
}

// ---------------- fusion: gate*proj of [query|graph|path], LN, fp32 out ---
__global__ __launch_bounds__(256) void k_fuse(const float* __restrict__ query,
    const float* __restrict__ graphr, const float* __restrict__ pathr,
    const float* __restrict__ gw, const float* __restrict__ gb,
    const float* __restrict__ pw, const float* __restrict__ pb,
    const float* __restrict__ g, const float* __restrict__ bb,
    float* __restrict__ out){
  __shared__ float comb[WH3];
  __shared__ float red[4];
  int b=blockIdx.x, t=threadIdx.x;
  for(int i=t;i<WH;i+=256){
    comb[i]       = query[(size_t)b*WH+i];
    comb[WH+i]    = graphr[(size_t)b*WH+i];
    comb[2*WH+i]  = pathr[(size_t)b*WH+i];
  }
  __syncthreads();
  float vals[3];
  #pragma unroll
  for(int jo=0;jo<3;++jo){
    int j=jo*256+t;
    float ag=0.f, ap=0.f;
    const float* gwp = gw + j;
    const float* pwp = pw + j;
    #pragma unroll 4
    for(int i=0;i<WH3;++i){ float a=comb[i];
      ag += a*gwp[(size_t)i*WH]; ap += a*pwp[(size_t)i*WH]; }
    ag += gb[j]; ap += pb[j];
    float sg = 1.f/(1.f+__expf(-ag));
    vals[jo]=sg*ap;
  }
  float s = block_sum256(vals[0]+vals[1]+vals[2], red);
  float m = s*(1.f/768.f);
  float d0=vals[0]-m,d1=vals[1]-m,d2=vals[2]-m;
  float v = block_sum256(d0*d0+d1*d1+d2*d2, red)*(1.f/768.f);
  float inv = rsqrtf(v+1e-5f);
  #pragma unroll
  for(int jo=0;jo<3;++jo){
    int j=jo*256+t;
    out[(size_t)b*WH+j] = (vals[jo]-m)*inv*g[j]+bb[j];
  }
}

extern "C" void kernel_launch(void* const* d_in, const int* in_sizes, int n_in,
                              void* d_out, int out_size, void* d_ws, size_t ws_size,
                              hipStream_t stream){
  const float* query  =(const float*)d_in[0];
  const float* nf     =(const float*)d_in[1];
  const int*   ei     =(const int*)  d_in[2];
  const int*   bidx   =(const int*)  d_in[3];
  const float* gr_wq  =(const float*)d_in[4];
  const float* gr_bq  =(const float*)d_in[5];
  const float* gr_aq_w=(const float*)d_in[6];
  const float* gr_aq_b=(const float*)d_in[7];
  const float* gr_ak_w=(const float*)d_in[8];
  const float* gr_ak_b=(const float*)d_in[9];
  const float* gr_av_w=(const float*)d_in[10];
  const float* gr_av_b=(const float*)d_in[11];
  const float* gr_ao_w=(const float*)d_in[12];
  const float* gr_ao_b=(const float*)d_in[13];
  const float* gr_ln_g=(const float*)d_in[14];
  const float* gr_ln_b=(const float*)d_in[15];
  const float* pf_wq  =(const float*)d_in[16];
  const float* pf_bq  =(const float*)d_in[17];
  const float* pf_wn  =(const float*)d_in[18];
  const float* pf_bn  =(const float*)d_in[19];
  const float* pf_a1_w=(const float*)d_in[20];
  const float* pf_a1_b=(const float*)d_in[21];
  const float* pf_a2_w=(const float*)d_in[22];
  const float* pf_a2_b=(const float*)d_in[23];
  const float* pf_ln_g=(const float*)d_in[24];
  const float* pf_ln_b=(const float*)d_in[25];
  const float* fu_gw  =(const float*)d_in[26];
  const float* fu_gb  =(const float*)d_in[27];
  const float* fu_pw  =(const float*)d_in[28];
  const float* fu_pb  =(const float*)d_in[29];
  const float* fu_ln_g=(const float*)d_in[30];
  const float* fu_ln_b=(const float*)d_in[31];
  float* out =(float*)d_out;

  float* w=(float*)d_ws;
  size_t o=0;
  float* qp     =w+o; o+=WB*WH;
  float* qp2    =w+o; o+=WB*WH;
  float* q      =w+o; o+=WB*WH;
  float* wq2    =w+o; o+=WB*WH;
  float* qkvec  =w+o; o+=(size_t)WB*WH*WHEADS;
  float* sconst =w+o; o+=WB*WHEADS;
  float* nconst =w+o; o+=64;
  float* qn     =w+o; o+=64;
  float* s      =w+o; o+=(size_t)WN*WHEADS;
  float* numer  =w+o; o+=WN;
  float* nrm    =w+o; o+=WN;
  float* meannf =w+o; o+=WB*WH;
  float* rowmax =w+o; o+=WB*WHEADS;
  float* rowinv =w+o; o+=WB*WHEADS;
  float* wnf    =w+o; o+=(size_t)WB*WHEADS*WH;
  float* ctx    =w+o; o+=WB*WH;
  float* graphr =w+o; o+=WB*WH;
  float* mpaths =w+o; o+=WB*WH;
  float* t1     =w+o; o+=WB*WH;
  float* agg    =w+o; o+=WB*WH;
  float* bmean  =w+o; o+=WB*WH;
  float* pathr  =w+o; o+=WB*WH;
  int* iw=(int*)(w+o);
  int* firstedge=iw; iw+=WN;
  int* cntb     =iw; iw+=64;
  int* starts   =iw; iw+=128;
  int* cntpath  =iw; iw+=64;

  dim3 blk(256);
  k_init   <<<768,blk,0,stream>>>(wnf, meannf, firstedge, cntb);
  k_rowgemm<<<WB,blk,0,stream>>>(query, gr_wq, gr_bq, qp, WH,0,0,nullptr,0,nullptr,nullptr);
  k_rowgemm<<<WB,blk,0,stream>>>(query, pf_wq, pf_bq, qp2, WH,0,0,nullptr,0,nullptr,nullptr);
  k_rowgemm<<<WB,blk,0,stream>>>(qp, gr_aq_w, gr_aq_b, q, WH,0,0,nullptr,0,nullptr,nullptr);
  k_rowgemm<<<WB,blk,0,stream>>>(qp2, pf_wn, nullptr, wq2, WH,1,0,nullptr,0,nullptr,nullptr);
  k_qkvec  <<<dim3(24,32),blk,0,stream>>>(q, gr_ak_w, gr_ak_b, qkvec, sconst);
  k_qmisc  <<<WB,blk,0,stream>>>(qp2, pf_bn, nconst, qn);
  k_node1  <<<WN/64,blk,0,stream>>>(nf, bidx, qkvec, wq2, sconst, nconst, s, numer, meannf, cntb);
  k_norm   <<<WN/128,blk,0,stream>>>(nf, pf_wn, pf_bn, nrm);
  k_stats  <<<WB*WHEADS,blk,0,stream>>>(s, rowmax, rowinv);
  k_node2  <<<WB*8,blk,0,stream>>>(nf, s, rowmax, rowinv, wnf);
  k_rowgemm<<<WB,blk,0,stream>>>(wnf, gr_av_w, gr_av_b, ctx, WH,0,1,nullptr,0,nullptr,nullptr);
  k_rowgemm<<<WB,blk,0,stream>>>(ctx, gr_ao_w, gr_ao_b, graphr, WH,0,0,nullptr,2,gr_ln_g,gr_ln_b);
  k_top3   <<<WB,blk,0,stream>>>(numer, nrm, qn, starts);
  k_edges  <<<WE/256,blk,0,stream>>>(ei, bidx, firstedge);
  k_path   <<<WB,blk,0,stream>>>(starts, firstedge, ei+WE, nf, mpaths, cntpath);
  k_rowgemm<<<WB,blk,0,stream>>>(mpaths, pf_a1_w, pf_a1_b, t1, WH,0,0,nullptr,1,nullptr,nullptr);
  k_rowgemm<<<WB,blk,0,stream>>>(t1, pf_a2_w, pf_a2_b, agg, WH,0,0,nullptr,0,nullptr,nullptr);
  k_rowgemm<<<WB,blk,0,stream>>>(meannf, pf_wn, pf_bn, bmean, WH,0,0,cntb,0,nullptr,nullptr);
  k_selln  <<<WB,blk,0,stream>>>(agg, bmean, cntpath, pf_ln_g, pf_ln_b, pathr);
  k_fuse   <<<WB,blk,0,stream>>>(query, graphr, pathr, fu_gw, fu_gb, fu_pw, fu_pb,
                                 fu_ln_g, fu_ln_b, out);
}

// Round 3
// 2050.934 us; speedup vs baseline: 2.2198x; 2.2198x over previous
//
#include <hip/hip_runtime.h>
#include <hip/hip_bf16.h>

#define WB 32
#define WNPB 2048
#define WN 65536
#define WH 768
#define WHEADS 8
#define WDH 96
#define WE 1048576
#define WH3 2304
#define SCALE_QK 0.10206207261596577f

typedef float f32x4 __attribute__((ext_vector_type(4)));
typedef short bf16x8 __attribute__((ext_vector_type(8)));

__device__ __forceinline__ unsigned short f2bf(float x){
  __hip_bfloat16 h = __float2bfloat16(x);
  return *reinterpret_cast<unsigned short*>(&h);
}
__device__ __forceinline__ float bf2f(unsigned short u){
  __hip_bfloat16 h; *reinterpret_cast<unsigned short*>(&h) = u;
  return __bfloat162float(h);
}

__device__ __forceinline__ float wave_sum64(float v){
  #pragma unroll
  for(int o=32;o;o>>=1) v += __shfl_xor(v,o,64);
  return v;
}
__device__ __forceinline__ float block_sum256(float v, float* red){
  v = wave_sum64(v);
  __syncthreads();
  if((threadIdx.x&63)==0) red[threadIdx.x>>6]=v;
  __syncthreads();
  return red[0]+red[1]+red[2]+red[3];
}
__device__ __forceinline__ float block_max256(float v, float* red){
  #pragma unroll
  for(int o=32;o;o>>=1) v = fmaxf(v,__shfl_xor(v,o,64));
  __syncthreads();
  if((threadIdx.x&63)==0) red[threadIdx.x>>6]=v;
  __syncthreads();
  return fmaxf(fmaxf(red[0],red[1]),fmaxf(red[2],red[3]));
}

// ---------------- init: zero accumulators, first_edge = E ----------------
__global__ __launch_bounds__(256) void k_init(float* wnf, float* meannf,
                                              int* firstedge, int* cntb){
  int t = blockIdx.x*256+threadIdx.x;
  if(t < WB*WHEADS*WH) wnf[t]=0.f;
  if(t < WB*WH) meannf[t]=0.f;
  if(t < WN) firstedge[t]=WE;
  if(t < WB) cntb[t]=0;
}

// ---------------- prep: wnT_hi/lo[n][k] = bf16 hi/lo of wn[k][n] ----------
__global__ __launch_bounds__(256) void k_prepw(const float* __restrict__ wn,
    unsigned short* __restrict__ th, unsigned short* __restrict__ tl){
  __shared__ float tile[64][68];
  int kt = blockIdx.x, nt = blockIdx.y, t = threadIdx.x;
  {
    int r = t>>2, q = t&3;
    const float4* src = (const float4*)(wn + (size_t)(kt*64 + r)*WH + nt*64 + q*16);
    float4 v0=src[0], v1=src[1], v2=src[2], v3=src[3];
    float* d = &tile[r][q*16];
    d[0]=v0.x; d[1]=v0.y; d[2]=v0.z; d[3]=v0.w;
    d[4]=v1.x; d[5]=v1.y; d[6]=v1.z; d[7]=v1.w;
    d[8]=v2.x; d[9]=v2.y; d[10]=v2.z; d[11]=v2.w;
    d[12]=v3.x; d[13]=v3.y; d[14]=v3.z; d[15]=v3.w;
  }
  __syncthreads();
  {
    int n = t>>2, q = t&3;
    #pragma unroll
    for(int e=0;e<16;++e){
      int kl = q*16 + e;
      float x = tile[kl][n];
      unsigned short h = f2bf(x);
      unsigned short l = f2bf(x - bf2f(h));
      size_t di = (size_t)(nt*64 + n)*WH + kt*64 + kl;
      th[di] = h; tl[di] = l;
    }
  }
}

// ---------------- 32-row GEMM, weights read once: C[b][j]=A[b]@W+bias -----
// grid 12 blocks (64-j tiles); 64 j-lanes x 4 groups of 8 batches.
__global__ __launch_bounds__(256) void k_gemm32(
    const float* __restrict__ A, const float* __restrict__ W,
    const float* __restrict__ bias, float* __restrict__ C,
    int relu, const int* __restrict__ cntb){
  __shared__ float a_t[WH*32];
  int t = threadIdx.x;
  for(int idx=t; idx<WH*32; idx+=256){
    int b = idx & 31, i = idx >> 5;
    float v = A[(size_t)b*WH + i];
    if(cntb){ int c = cntb[b]; v *= 1.f/(float)(c>1?c:1); }
    a_t[i*32 + b] = v;
  }
  __syncthreads();
  int jl = t & 63, bg = t >> 6;
  int j = blockIdx.x*64 + jl;
  float acc[8];
  #pragma unroll
  for(int k=0;k<8;++k) acc[k]=0.f;
  #pragma unroll 4
  for(int i=0;i<WH;++i){
    float w = W[(size_t)i*WH + j];
    const float4* ap = (const float4*)&a_t[i*32 + bg*8];
    float4 a0 = ap[0], a1 = ap[1];
    acc[0]+=a0.x*w; acc[1]+=a0.y*w; acc[2]+=a0.z*w; acc[3]+=a0.w*w;
    acc[4]+=a1.x*w; acc[5]+=a1.y*w; acc[6]+=a1.z*w; acc[7]+=a1.w*w;
  }
  float bj = bias? bias[j] : 0.f;
  #pragma unroll
  for(int bb=0;bb<8;++bb){
    float v = acc[bb] + bj;
    if(relu) v = fmaxf(v, 0.f);
    C[(size_t)(bg*8+bb)*WH + j] = v;
  }
}

// ---------------- 32-row GEMM vs W^T: C[b][i]=sum_j A[b][j]*W[i][j] -------
__global__ __launch_bounds__(256) void k_gemm32t(
    const float* __restrict__ A, const float* __restrict__ W,
    float* __restrict__ C){
  __shared__ float a_t[WH*32];
  int t = threadIdx.x;
  for(int idx=t; idx<WH*32; idx+=256){
    int b = idx & 31, i = idx >> 5;
    a_t[i*32 + b] = A[(size_t)b*WH + i];
  }
  __syncthreads();
  int il = t & 63, bg = t >> 6;
  int i = blockIdx.x*64 + il;
  const float4* Wr = (const float4*)(W + (size_t)i*WH);
  float acc[8];
  #pragma unroll
  for(int k=0;k<8;++k) acc[k]=0.f;
  #pragma unroll 2
  for(int j4=0;j4<WH/4;++j4){
    float4 wv = Wr[j4];
    float ws[4] = {wv.x, wv.y, wv.z, wv.w};
    #pragma unroll
    for(int c=0;c<4;++c){
      const float4* ap = (const float4*)&a_t[(j4*4+c)*32 + bg*8];
      float4 a0 = ap[0], a1 = ap[1];
      float w = ws[c];
      acc[0]+=a0.x*w; acc[1]+=a0.y*w; acc[2]+=a0.z*w; acc[3]+=a0.w*w;
      acc[4]+=a1.x*w; acc[5]+=a1.y*w; acc[6]+=a1.z*w; acc[7]+=a1.w*w;
    }
  }
  #pragma unroll
  for(int bb=0;bb<8;++bb) C[(size_t)(bg*8+bb)*WH + i] = acc[bb];
}

// ---------------- qk_vec[b,i,h] = sum_d q[b,h*96+d]*ak_w[i,h*96+d] --------
__global__ __launch_bounds__(256) void k_qkvec(const float* __restrict__ q,
    const float* __restrict__ akw, const float* __restrict__ akb,
    float* __restrict__ qkvec, float* __restrict__ sconst){
  __shared__ float qlds[800];
  int b=blockIdx.y, ic=blockIdx.x, t=threadIdx.x;
  for(int idx=t; idx<WH; idx+=256){
    int h2 = idx/WDH, d = idx - h2*WDH;
    qlds[h2*100 + d] = q[(size_t)b*WH + idx];
  }
  __syncthreads();
  int il=t>>3, h=t&7;
  int i=ic*32+il;
  const float4* wr4 = (const float4*)(akw + (size_t)i*WH + h*WDH);
  float acc=0.f;
  #pragma unroll
  for(int u=0;u<WDH/4;++u){
    float4 w = wr4[u];
    const float4* qv4 = (const float4*)&qlds[h*100 + u*4];
    float4 qv = qv4[0];
    acc += w.x*qv.x + w.y*qv.y + w.z*qv.z + w.w*qv.w;
  }
  qkvec[((size_t)b*WH+i)*WHEADS + h] = acc;
  if(ic==0 && il==0){
    float sc=0.f;
    for(int d=0;d<WDH;++d) sc += qlds[h*100+d]*akb[h*WDH+d];
    sconst[b*WHEADS+h]=sc;
  }
}

// ---------------- numer_const[b]=qp2.bn ; qn[b]=max(||qp2||,1e-8) ---------
__global__ __launch_bounds__(256) void k_qmisc(const float* __restrict__ qp2,
    const float* __restrict__ pbn, float* __restrict__ nconst, float* __restrict__ qn){
  __shared__ float red[4];
  int b=blockIdx.x, t=threadIdx.x;
  float s1=0.f,s2=0.f;
  for(int i=t;i<WH;i+=256){ float v=qp2[(size_t)b*WH+i]; s1+=v*pbn[i]; s2+=v*v; }
  s1=block_sum256(s1,red);
  s2=block_sum256(s2,red);
  if(t==0){ nconst[b]=s1; qn[b]=fmaxf(sqrtf(s2),1e-8f); }
}

// ---------------- MFMA bf16 hi/lo: nn[n]=||nf@wn+bn|| ---------------------
// 128x256x64 tile, 8 waves (2x4), wave-tile 64x64, 3 col-passes.
__global__ __launch_bounds__(512) void k_normM(
    const float* __restrict__ nf, const uint4* __restrict__ wnTh,
    const uint4* __restrict__ wnTl, const float* __restrict__ bn,
    float* __restrict__ nnout){
  __shared__ uint4 Ah[128*8], Al[128*8];
  __shared__ uint4 Bh[256*8], Bl[256*8];
  __shared__ float sqred[128];
  int t = threadIdx.x, lane = t & 63, wid = t >> 6;
  int wr = wid >> 2, wc = wid & 3;
  int l15 = lane & 15, lg = lane >> 4;
  int r0 = blockIdx.x * 128;
  if(t < 128) sqred[t] = 0.f;
  float sqr[4][4];
  #pragma unroll
  for(int mi=0;mi<4;++mi)
    #pragma unroll
    for(int r=0;r<4;++r) sqr[mi][r]=0.f;

  for(int ct=0; ct<3; ++ct){
    f32x4 acc[4][4];
    #pragma unroll
    for(int mi=0;mi<4;++mi)
      #pragma unroll
      for(int ni=0;ni<4;++ni) acc[mi][ni] = (f32x4){0.f,0.f,0.f,0.f};

    for(int kt=0; kt<12; ++kt){
      __syncthreads();
      { // stage A (fp32 -> hi/lo bf16), rows r0..r0+127, k = kt*64..+64
        int r = t >> 2, q = t & 3;
        const float4* src = (const float4*)(nf + (size_t)(r0 + r)*WH + kt*64 + q*16);
        float4 v0=src[0], v1=src[1], v2=src[2], v3=src[3];
        float vals[16] = {v0.x,v0.y,v0.z,v0.w, v1.x,v1.y,v1.z,v1.w,
                          v2.x,v2.y,v2.z,v2.w, v3.x,v3.y,v3.z,v3.w};
        unsigned int hd[8], ld_[8];
        #pragma unroll
        for(int e=0;e<8;++e){
          float x0 = vals[2*e], x1 = vals[2*e+1];
          unsigned short h0 = f2bf(x0), h1 = f2bf(x1);
          unsigned short l0 = f2bf(x0 - bf2f(h0)), l1 = f2bf(x1 - bf2f(h1));
          hd[e] = (unsigned)h0 | ((unsigned)h1 << 16);
          ld_[e] = (unsigned)l0 | ((unsigned)l1 << 16);
        }
        int sw = r & 7;
        uint4 uh0; uh0.x=hd[0]; uh0.y=hd[1]; uh0.z=hd[2]; uh0.w=hd[3];
        uint4 uh1; uh1.x=hd[4]; uh1.y=hd[5]; uh1.z=hd[6]; uh1.w=hd[7];
        uint4 ul0; ul0.x=ld_[0]; ul0.y=ld_[1]; ul0.z=ld_[2]; ul0.w=ld_[3];
        uint4 ul1; ul1.x=ld_[4]; ul1.y=ld_[5]; ul1.z=ld_[6]; ul1.w=ld_[7];
        Ah[r*8 + ((2*q  ) ^ sw)] = uh0;
        Ah[r*8 + ((2*q+1) ^ sw)] = uh1;
        Al[r*8 + ((2*q  ) ^ sw)] = ul0;
        Al[r*8 + ((2*q+1) ^ sw)] = ul1;
      }
      { // stage B (preconverted), n = ct*256..+256, k = kt*64..+64
        int n = t >> 1, hh = t & 1;
        size_t gi = ((size_t)(ct*256 + n)*WH + kt*64 + hh*32) >> 3;
        int sw = n & 7;
        uint4 b0 = wnTh[gi], b1 = wnTh[gi+1], b2 = wnTh[gi+2], b3 = wnTh[gi+3];
        Bh[n*8 + ((4*hh  ) ^ sw)] = b0;
        Bh[n*8 + ((4*hh+1) ^ sw)] = b1;
        Bh[n*8 + ((4*hh+2) ^ sw)] = b2;
        Bh[n*8 + ((4*hh+3) ^ sw)] = b3;
        uint4 c0 = wnTl[gi], c1 = wnTl[gi+1], c2 = wnTl[gi+2], c3 = wnTl[gi+3];
        Bl[n*8 + ((4*hh  ) ^ sw)] = c0;
        Bl[n*8 + ((4*hh+1) ^ sw)] = c1;
        Bl[n*8 + ((4*hh+2) ^ sw)] = c2;
        Bl[n*8 + ((4*hh+3) ^ sw)] = c3;
      }
      __syncthreads();
      #pragma unroll
      for(int ks=0; ks<2; ++ks){
        bf16x8 ah[4], al_[4], bh[4], bl_[4];
        #pragma unroll
        for(int mi=0;mi<4;++mi){
          int row = wr*64 + mi*16 + l15;
          int u = (ks*4 + lg) ^ (row & 7);
          ah[mi]  = ((const bf16x8*)Ah)[row*8 + u];
          al_[mi] = ((const bf16x8*)Al)[row*8 + u];
        }
        #pragma unroll
        for(int ni=0;ni<4;++ni){
          int row = wc*64 + ni*16 + l15;
          int u = (ks*4 + lg) ^ (row & 7);
          bh[ni]  = ((const bf16x8*)Bh)[row*8 + u];
          bl_[ni] = ((const bf16x8*)Bl)[row*8 + u];
        }
        #pragma unroll
        for(int mi=0;mi<4;++mi)
          #pragma unroll
          for(int ni=0;ni<4;++ni){
            acc[mi][ni] = __builtin_amdgcn_mfma_f32_16x16x32_bf16(ah[mi],  bh[ni],  acc[mi][ni], 0,0,0);
            acc[mi][ni] = __builtin_amdgcn_mfma_f32_16x16x32_bf16(ah[mi],  bl_[ni], acc[mi][ni], 0,0,0);
            acc[mi][ni] = __builtin_amdgcn_mfma_f32_16x16x32_bf16(al_[mi], bh[ni],  acc[mi][ni], 0,0,0);
          }
      }
    }
    // epilogue for this col-pass: add bias, square, accumulate per-row
    #pragma unroll
    for(int ni=0;ni<4;++ni){
      int col = ct*256 + wc*64 + ni*16 + l15;
      float bj = bn[col];
      #pragma unroll
      for(int mi=0;mi<4;++mi)
        #pragma unroll
        for(int r=0;r<4;++r){
          float v = acc[mi][ni][r] + bj;
          sqr[mi][r] += v*v;
        }
    }
  }
  // reduce across the 16 col-lanes of each row-group
  #pragma unroll
  for(int mi=0;mi<4;++mi)
    #pragma unroll
    for(int r=0;r<4;++r){
      float v = sqr[mi][r];
      v += __shfl_xor(v, 1, 64);
      v += __shfl_xor(v, 2, 64);
      v += __shfl_xor(v, 4, 64);
      v += __shfl_xor(v, 8, 64);
      sqr[mi][r] = v;
    }
  if(l15 == 0){
    #pragma unroll
    for(int mi=0;mi<4;++mi)
      #pragma unroll
      for(int r=0;r<4;++r){
        int row = wr*64 + mi*16 + lg*4 + r;
        atomicAdd(&sqred[row], sqr[mi][r]);
      }
  }
  __syncthreads();
  if(t < 128) nnout[r0 + t] = fmaxf(sqrtf(sqred[t]), 1e-8f);
}

// ---------------- node pass 1: scores, numer, per-batch nf sums -----------
__global__ __launch_bounds__(256) void k_node1(
    const float* __restrict__ nf, const int* __restrict__ bidx,
    const float* __restrict__ qkvec, const float* __restrict__ wq2,
    const float* __restrict__ sconst, const float* __restrict__ nconst,
    float* __restrict__ s_out, float* __restrict__ numer,
    float* __restrict__ meannf, int* __restrict__ cntb){
  __shared__ float m_lds[4][WH];
  int lane = threadIdx.x&63, w = threadIdx.x>>6;
  int n0 = blockIdx.x*64;
  int b = bidx[n0];
  const float* qkb = qkvec + (size_t)b*WH*WHEADS;
  const float4* wqb4 = (const float4*)(wq2 + (size_t)b*WH);
  float sc[8];
  #pragma unroll
  for(int h=0;h<8;++h) sc[h]=sconst[b*WHEADS+h];
  float ncst = nconst[b];
  float macc[12];
  #pragma unroll
  for(int i=0;i<12;++i) macc[i]=0.f;
  for(int q_=0;q_<16;++q_){
    int n = n0 + w*16 + q_;
    const float4* nfr = (const float4*)(nf + (size_t)n*WH);
    float acc[8]; float anu=0.f;
    #pragma unroll
    for(int h=0;h<8;++h) acc[h]=0.f;
    #pragma unroll
    for(int tt=0;tt<3;++tt){
      int i4 = lane + 64*tt;
      float4 xv = nfr[i4];
      float4 wv = wqb4[i4];
      const float4* qk4 = (const float4*)(qkb + (size_t)i4*32);
      float xs[4]={xv.x,xv.y,xv.z,xv.w};
      float ws[4]={wv.x,wv.y,wv.z,wv.w};
      #pragma unroll
      for(int u=0;u<4;++u){
        float x = xs[u];
        float4 qa = qk4[2*u], qb = qk4[2*u+1];
        acc[0]+=x*qa.x; acc[1]+=x*qa.y; acc[2]+=x*qa.z; acc[3]+=x*qa.w;
        acc[4]+=x*qb.x; acc[5]+=x*qb.y; acc[6]+=x*qb.z; acc[7]+=x*qb.w;
        anu += x*ws[u];
        macc[tt*4+u]+=x;
      }
    }
    #pragma unroll
    for(int h=0;h<8;++h) acc[h]=wave_sum64(acc[h]);
    anu = wave_sum64(anu);
    if(lane==0){
      #pragma unroll
      for(int h=0;h<8;++h) s_out[(size_t)n*8+h] = SCALE_QK*(acc[h]+sc[h]);
      numer[n] = anu + ncst;
    }
  }
  #pragma unroll
  for(int tt=0;tt<3;++tt){
    #pragma unroll
    for(int u=0;u<4;++u) m_lds[w][4*lane+256*tt+u]=macc[tt*4+u];
  }
  __syncthreads();
  for(int i=threadIdx.x;i<WH;i+=256)
    atomicAdd(&meannf[(size_t)b*WH+i],
              m_lds[0][i]+m_lds[1][i]+m_lds[2][i]+m_lds[3][i]);
  if(threadIdx.x==0) atomicAdd(&cntb[b],64);
}

// ---------------- softmax stats per (b,h) over the batch's 2048 nodes -----
__global__ __launch_bounds__(256) void k_stats(const float* __restrict__ s,
    float* __restrict__ rowmax, float* __restrict__ rowinv){
  __shared__ float red[4];
  int b = blockIdx.x>>3, h = blockIdx.x&7;
  const float* sp = s + (size_t)b*WNPB*8 + h;
  float mx=-3e38f;
  for(int i=threadIdx.x;i<WNPB;i+=256) mx=fmaxf(mx, sp[(size_t)i*8]);
  mx = block_max256(mx, red);
  float se=0.f;
  for(int i=threadIdx.x;i<WNPB;i+=256) se += __expf(sp[(size_t)i*8]-mx);
  se = block_sum256(se, red);
  if(threadIdx.x==0){ rowmax[blockIdx.x]=mx; rowinv[blockIdx.x]=1.f/se; }
}

// ---------------- node pass 2: wnf[b,h,:] += softmax(s)[n,h]*nf[n,:] ------
__global__ __launch_bounds__(256) void k_node2(
    const float* __restrict__ nf, const float* __restrict__ s,
    const float* __restrict__ rowmax, const float* __restrict__ rowinv,
    float* __restrict__ wnf){
  __shared__ float p_lds[128*8];
  int b = blockIdx.x >> 4, ch = blockIdx.x & 15;
  int t = threadIdx.x;
  int n0 = b*WNPB + ch*128;
  for(int idx=t; idx<1024; idx+=256){
    int nl = idx >> 3, h = idx & 7;
    p_lds[idx] = __expf(s[(size_t)(n0+nl)*8 + h] - rowmax[b*8+h]) * rowinv[b*8+h];
  }
  __syncthreads();
  float racc[24];
  #pragma unroll
  for(int i=0;i<24;++i) racc[i]=0.f;
  const float* nfb = nf + (size_t)n0*WH;
  #pragma unroll 2
  for(int m=0;m<128;++m){
    float x0 = nfb[(size_t)m*WH + t];
    float x1 = nfb[(size_t)m*WH + t + 256];
    float x2 = nfb[(size_t)m*WH + t + 512];
    const float* pm = p_lds + m*8;
    #pragma unroll
    for(int h=0;h<8;++h){
      float p = pm[h];
      racc[h*3+0] += p*x0; racc[h*3+1] += p*x1; racc[h*3+2] += p*x2;
    }
  }
  float* wb = wnf + (size_t)b*WHEADS*WH;
  #pragma unroll
  for(int h=0;h<8;++h){
    atomicAdd(&wb[h*WH + t],       racc[h*3+0]);
    atomicAdd(&wb[h*WH + t + 256], racc[h*3+1]);
    atomicAdd(&wb[h*WH + t + 512], racc[h*3+2]);
  }
}

// ---------------- ctx: head-structured 32-row GEMM ------------------------
__global__ __launch_bounds__(256) void k_ctx(const float* __restrict__ wnf,
    const float* __restrict__ W, const float* __restrict__ bias,
    float* __restrict__ C){
  __shared__ float a_lds[WHEADS*WH];
  int b = blockIdx.x, t = threadIdx.x;
  const float* Ar = wnf + (size_t)b*WHEADS*WH;
  for(int i=t;i<WHEADS*WH;i+=256) a_lds[i]=Ar[i];
  __syncthreads();
  #pragma unroll
  for(int jo=0;jo<3;++jo){
    int j = jo*256+t;
    const float* ap = a_lds + (j/WDH)*WH;
    const float* wp = W + j;
    float acc=0.f;
    #pragma unroll 4
    for(int i=0;i<WH;++i) acc += ap[i]*wp[(size_t)i*WH];
    C[(size_t)b*WH+j] = acc + bias[j];
  }
}

// ---------------- per-batch top-3 cosine sim ------------------------------
__device__ __forceinline__ void top3_insert(float v, int i, float* tv, int* ti){
  if (v>tv[0] || (v==tv[0] && i<ti[0])){
    tv[2]=tv[1]; ti[2]=ti[1]; tv[1]=tv[0]; ti[1]=ti[0]; tv[0]=v; ti[0]=i;
  } else if (v>tv[1] || (v==tv[1] && i<ti[1])){
    tv[2]=tv[1]; ti[2]=ti[1]; tv[1]=v; ti[1]=i;
  } else if (v>tv[2] || (v==tv[2] && i<ti[2])){
    tv[2]=v; ti[2]=i;
  }
}
__global__ __launch_bounds__(256) void k_top3(const float* __restrict__ numer,
    const float* __restrict__ nrm, const float* __restrict__ qn,
    int* __restrict__ starts){
  __shared__ float sv[256][3];
  __shared__ int   si[256][3];
  int b=blockIdx.x, t=threadIdx.x;
  float qv = qn[b];
  float tv[3]={-3e38f,-3e38f,-3e38f};
  int   ti[3]={0x7fffffff,0x7fffffff,0x7fffffff};
  for(int u=t;u<WNPB;u+=256){
    int n=b*WNPB+u;
    float v = numer[n]/(qv*nrm[n]);
    top3_insert(v,n,tv,ti);
  }
  sv[t][0]=tv[0];sv[t][1]=tv[1];sv[t][2]=tv[2];
  si[t][0]=ti[0];si[t][1]=ti[1];si[t][2]=ti[2];
  __syncthreads();
  for(int st=128;st;st>>=1){
    if(t<st){
      #pragma unroll
      for(int k=0;k<3;++k) top3_insert(sv[t+st][k], si[t+st][k], tv, ti);
      sv[t][0]=tv[0];sv[t][1]=tv[1];sv[t][2]=tv[2];
      si[t][0]=ti[0];si[t][1]=ti[1];si[t][2]=ti[2];
    }
    __syncthreads();
  }
  if(t<3) starts[b*3+t]=si[0][t];
}

// ---------------- edge scan + zero fuse accumulators ----------------------
__global__ __launch_bounds__(256) void k_edges(const int* __restrict__ ei,
    const int* __restrict__ bidx, int* __restrict__ firstedge,
    float* __restrict__ fzero){
  int e = blockIdx.x*256+threadIdx.x;
  if(e < 2*WB*WH) fzero[e] = 0.f;
  if(e<WE){
    int s=ei[e], d=ei[WE+e];
    if(bidx[s]==bidx[d]) atomicMin(&firstedge[s], e);
  }
}

// ---------------- per-batch path features ---------------------------------
__global__ __launch_bounds__(256) void k_path(const int* __restrict__ starts,
    const int* __restrict__ firstedge, const int* __restrict__ dst,
    const float* __restrict__ nf, float* __restrict__ mpaths,
    int* __restrict__ cntpath){
  int b=blockIdx.x;
  int sl[3], nl[3], vl[3]; int cnt=0;
  #pragma unroll
  for(int k=0;k<3;++k){
    int st = starts[b*3+k];
    int fe = firstedge[st];
    int valid = fe<WE;
    sl[k]=st; nl[k]= valid? dst[fe] : 0; vl[k]=valid; cnt+=valid;
  }
  float inv = 1.f/(float)(cnt>1?cnt:1);
  for(int j=threadIdx.x;j<WH;j+=256){
    float acc=0.f;
    #pragma unroll
    for(int k=0;k<3;++k)
      if(vl[k]) acc += 0.5f*(nf[(size_t)sl[k]*WH+j] + nf[(size_t)nl[k]*WH+j]);
    mpaths[(size_t)b*WH+j]=acc*inv;
  }
  if(threadIdx.x==0) cntpath[b]=cnt;
}

// ---------------- select + LayerNorm (cntpath nullable) -------------------
__global__ __launch_bounds__(256) void k_selln(const float* __restrict__ agg,
    const float* __restrict__ bmean, const int* __restrict__ cntpath,
    const float* __restrict__ g, const float* __restrict__ bb,
    float* __restrict__ out){
  __shared__ float red[4];
  int b=blockIdx.x, t=threadIdx.x;
  const float* src = agg;
  if(cntpath && cntpath[b]<=0) src = bmean;
  src += (size_t)b*WH;
  float x[3];
  #pragma unroll
  for(int jo=0;jo<3;++jo) x[jo]=src[jo*256+t];
  float s = block_sum256(x[0]+x[1]+x[2], red);
  float m = s*(1.f/768.f);
  float d0=x[0]-m,d1=x[1]-m,d2=x[2]-m;
  float v = block_sum256(d0*d0+d1*d1+d2*d2, red)*(1.f/768.f);
  float inv = rsqrtf(v+1e-5f);
  #pragma unroll
  for(int jo=0;jo<3;++jo){ int j=jo*256+t;
    out[(size_t)b*WH+j]=(x[jo]-m)*inv*g[j]+bb[j]; }
}

// ---------------- fusion matmuls: weights read once, K-chunked ------------
// grid (12 j-tiles, 4 k-chunks); facc[0]=gate-pre, facc[1]=proj-pre.
__global__ __launch_bounds__(256) void k_fuse_mm(
    const float* __restrict__ query, const float* __restrict__ graphr,
    const float* __restrict__ pathr, const float* __restrict__ gw,
    const float* __restrict__ pw, float* __restrict__ facc){
  __shared__ float c_t[576*32];
  int t = threadIdx.x;
  int jt = blockIdx.x, kc = blockIdx.y;
  for(int idx=t; idx<576*32; idx+=256){
    int b = idx & 31, ii = idx >> 5;
    int gi = kc*576 + ii;
    float v;
    if(gi < WH)        v = query [(size_t)b*WH + gi];
    else if(gi < 2*WH) v = graphr[(size_t)b*WH + gi - WH];
    else               v = pathr [(size_t)b*WH + gi - 2*WH];
    c_t[ii*32 + b] = v;
  }
  __syncthreads();
  int jl = t & 63, bg = t >> 6;
  int j = jt*64 + jl;
  float ag[8], ap[8];
  #pragma unroll
  for(int k=0;k<8;++k){ ag[k]=0.f; ap[k]=0.f; }
  #pragma unroll 2
  for(int ii=0;ii<576;++ii){
    size_t wi = (size_t)(kc*576 + ii)*WH + j;
    float wg = gw[wi], wp = pw[wi];
    const float4* cp = (const float4*)&c_t[ii*32 + bg*8];
    float4 a0 = cp[0], a1 = cp[1];
    ag[0]+=a0.x*wg; ag[1]+=a0.y*wg; ag[2]+=a0.z*wg; ag[3]+=a0.w*wg;
    ag[4]+=a1.x*wg; ag[5]+=a1.y*wg; ag[6]+=a1.z*wg; ag[7]+=a1.w*wg;
    ap[0]+=a0.x*wp; ap[1]+=a0.y*wp; ap[2]+=a0.z*wp; ap[3]+=a0.w*wp;
    ap[4]+=a1.x*wp; ap[5]+=a1.y*wp; ap[6]+=a1.z*wp; ap[7]+=a1.w*wp;
  }
  #pragma unroll
  for(int bb=0;bb<8;++bb){
    atomicAdd(&facc[(size_t)(bg*8+bb)*WH + j], ag[bb]);
    atomicAdd(&facc[(size_t)WB*WH + (size_t)(bg*8+bb)*WH + j], ap[bb]);
  }
}

// ---------------- fusion epilogue: sigmoid-gate, LN, fp32 out -------------
__global__ __launch_bounds__(256) void k_fuse_ep(const float* __restrict__ facc,
    const float* __restrict__ gb, const float* __restrict__ pb,
    const float* __restrict__ g, const float* __restrict__ bb,
    float* __restrict__ out){
  __shared__ float red[4];
  int b=blockIdx.x, t=threadIdx.x;
  float vals[3];
  #pragma unroll
  for(int jo=0;jo<3;++jo){
    int j=jo*256+t;
    float ag = facc[(size_t)b*WH + j] + gb[j];
    float ap = facc[(size_t)WB*WH + (size_t)b*WH + j] + pb[j];
    float sg = 1.f/(1.f+__expf(-ag));
    vals[jo]=sg*ap;
  }
  float s = block_sum256(vals[0]+vals[1]+vals[2], red);
  float m = s*(1.f/768.f);
  float d0=vals[0]-m,d1=vals[1]-m,d2=vals[2]-m;
  float v = block_sum256(d0*d0+d1*d1+d2*d2, red)*(1.f/768.f);
  float inv = rsqrtf(v+1e-5f);
  #pragma unroll
  for(int jo=0;jo<3;++jo){
    int j=jo*256+t;
    out[(size_t)b*WH+j] = (vals[jo]-m)*inv*g[j]+bb[j];
  }
}

extern "C" void kernel_launch(void* const* d_in, const int* in_sizes, int n_in,
                              void* d_out, int out_size, void* d_ws, size_t ws_size,
                              hipStream_t stream){
  const float* query  =(const float*)d_in[0];
  const float* nf     =(const float*)d_in[1];
  const int*   ei     =(const int*)  d_in[2];
  const int*   bidx   =(const int*)  d_in[3];
  const float* gr_wq  =(const float*)d_in[4];
  const float* gr_bq  =(const float*)d_in[5];
  const float* gr_aq_w=(const float*)d_in[6];
  const float* gr_aq_b=(const float*)d_in[7];
  const float* gr_ak_w=(const float*)d_in[8];
  const float* gr_ak_b=(const float*)d_in[9];
  const float* gr_av_w=(const float*)d_in[10];
  const float* gr_av_b=(const float*)d_in[11];
  const float* gr_ao_w=(const float*)d_in[12];
  const float* gr_ao_b=(const float*)d_in[13];
  const float* gr_ln_g=(const float*)d_in[14];
  const float* gr_ln_b=(const float*)d_in[15];
  const float* pf_wq  =(const float*)d_in[16];
  const float* pf_bq  =(const float*)d_in[17];
  const float* pf_wn  =(const float*)d_in[18];
  const float* pf_bn  =(const float*)d_in[19];
  const float* pf_a1_w=(const float*)d_in[20];
  const float* pf_a1_b=(const float*)d_in[21];
  const float* pf_a2_w=(const float*)d_in[22];
  const float* pf_a2_b=(const float*)d_in[23];
  const float* pf_ln_g=(const float*)d_in[24];
  const float* pf_ln_b=(const float*)d_in[25];
  const float* fu_gw  =(const float*)d_in[26];
  const float* fu_gb  =(const float*)d_in[27];
  const float* fu_pw  =(const float*)d_in[28];
  const float* fu_pb  =(const float*)d_in[29];
  const float* fu_ln_g=(const float*)d_in[30];
  const float* fu_ln_b=(const float*)d_in[31];
  float* out =(float*)d_out;

  float* w=(float*)d_ws;
  size_t o=0;
  // s/numer region, overlaid with wnT hi/lo bf16 planes (byte-exact):
  // wnT used only between k_prepw and k_normM; s/numer written by k_node1 after.
  float* sregion=w+o; o+=(size_t)WN*WHEADS + WN;   // 589824 floats
  float* s      = sregion;
  float* numer  = sregion + (size_t)WN*WHEADS;
  unsigned short* wnTh = (unsigned short*)sregion;                 // 768*768 ushort
  unsigned short* wnTl = ((unsigned short*)sregion) + (size_t)WH*WH;
  float* qp     =w+o; o+=WB*WH;
  float* qp2    =w+o; o+=WB*WH;
  float* q      =w+o; o+=WB*WH;
  float* wq2    =w+o; o+=WB*WH;
  float* qkvec  =w+o; o+=(size_t)WB*WH*WHEADS;     // overlaid: ctxo + fuse_acc
  float* ctxo   = qkvec;                           // dead after k_node1
  float* fuse_acc = qkvec + WB*WH;                 // 2*WB*WH floats
  float* sconst =w+o; o+=WB*WHEADS;
  float* nconst =w+o; o+=64;
  float* qn     =w+o; o+=64;
  float* nrm    =w+o; o+=WN;
  float* meannf =w+o; o+=WB*WH;
  float* rowmax =w+o; o+=WB*WHEADS;
  float* rowinv =w+o; o+=WB*WHEADS;
  float* wnf    =w+o; o+=(size_t)WB*WHEADS*WH;
  float* ctx    =w+o; o+=WB*WH;
  float* graphr =w+o; o+=WB*WH;
  float* mpaths =w+o; o+=WB*WH;
  float* t1     =w+o; o+=WB*WH;
  float* agg    =w+o; o+=WB*WH;
  float* bmean  =w+o; o+=WB*WH;
  float* pathr  =w+o; o+=WB*WH;
  int* iw=(int*)(w+o);
  int* firstedge=iw; iw+=WN;
  int* cntb     =iw; iw+=64;
  int* starts   =iw; iw+=128;
  int* cntpath  =iw; iw+=64;

  dim3 blk(256);
  k_init   <<<768,blk,0,stream>>>(wnf, meannf, firstedge, cntb);
  k_prepw  <<<dim3(12,12),blk,0,stream>>>(pf_wn, wnTh, wnTl);
  k_gemm32 <<<12,blk,0,stream>>>(query, gr_wq, gr_bq, qp, 0, nullptr);
  k_gemm32 <<<12,blk,0,stream>>>(query, pf_wq, pf_bq, qp2, 0, nullptr);
  k_gemm32 <<<12,blk,0,stream>>>(qp, gr_aq_w, gr_aq_b, q, 0, nullptr);
  k_gemm32t<<<12,blk,0,stream>>>(qp2, pf_wn, wq2);
  k_qkvec  <<<dim3(24,32),blk,0,stream>>>(q, gr_ak_w, gr_ak_b, qkvec, sconst);
  k_qmisc  <<<WB,blk,0,stream>>>(qp2, pf_bn, nconst, qn);
  k_normM  <<<WN/128,dim3(512),0,stream>>>(nf, (const uint4*)wnTh, (const uint4*)wnTl, pf_bn, nrm);
  k_node1  <<<WN/64,blk,0,stream>>>(nf, bidx, qkvec, wq2, sconst, nconst, s, numer, meannf, cntb);
  k_stats  <<<WB*WHEADS,blk,0,stream>>>(s, rowmax, rowinv);
  k_node2  <<<WB*16,blk,0,stream>>>(nf, s, rowmax, rowinv, wnf);
  k_ctx    <<<WB,blk,0,stream>>>(wnf, gr_av_w, gr_av_b, ctx);
  k_gemm32 <<<12,blk,0,stream>>>(ctx, gr_ao_w, gr_ao_b, ctxo, 0, nullptr);
  k_selln  <<<WB,blk,0,stream>>>(ctxo, ctxo, nullptr, gr_ln_g, gr_ln_b, graphr);
  k_top3   <<<WB,blk,0,stream>>>(numer, nrm, qn, starts);
  k_edges  <<<WE/256,blk,0,stream>>>(ei, bidx, firstedge, fuse_acc);
  k_path   <<<WB,blk,0,stream>>>(starts, firstedge, ei+WE, nf, mpaths, cntpath);
  k_gemm32 <<<12,blk,0,stream>>>(mpaths, pf_a1_w, pf_a1_b, t1, 1, nullptr);
  k_gemm32 <<<12,blk,0,stream>>>(t1, pf_a2_w, pf_a2_b, agg, 0, nullptr);
  k_gemm32 <<<12,blk,0,stream>>>(meannf, pf_wn, pf_bn, bmean, 0, cntb);
  k_selln  <<<WB,blk,0,stream>>>(agg, bmean, cntpath, pf_ln_g, pf_ln_b, pathr);
  k_fuse_mm<<<dim3(12,4),blk,0,stream>>>(query, graphr, pathr, fu_gw, fu_pw, fuse_acc);
  k_fuse_ep<<<WB,blk,0,stream>>>(fuse_acc, fu_gb, fu_pb, fu_ln_g, fu_ln_b, out);
}

// Round 4
// 1892.688 us; speedup vs baseline: 2.4054x; 1.0836x over previous
//
#include <hip/hip_runtime.h>
#include <hip/hip_bf16.h>

#define WB 32
#define WNPB 2048
#define WN 65536
#define WH 768
#define WHEADS 8
#define WDH 96
#define WE 1048576
#define WH3 2304
#define SCALE_QK 0.10206207261596577f

typedef float f32x4 __attribute__((ext_vector_type(4)));
typedef short bf16x8 __attribute__((ext_vector_type(8)));

__device__ __forceinline__ unsigned short f2bf(float x){
  __hip_bfloat16 h = __float2bfloat16(x);
  return *reinterpret_cast<unsigned short*>(&h);
}
__device__ __forceinline__ float bf2f(unsigned short u){
  __hip_bfloat16 h; *reinterpret_cast<unsigned short*>(&h) = u;
  return __bfloat162float(h);
}

__device__ __forceinline__ float wave_sum64(float v){
  #pragma unroll
  for(int o=32;o;o>>=1) v += __shfl_xor(v,o,64);
  return v;
}
__device__ __forceinline__ float block_sum256(float v, float* red){
  v = wave_sum64(v);
  __syncthreads();
  if((threadIdx.x&63)==0) red[threadIdx.x>>6]=v;
  __syncthreads();
  return red[0]+red[1]+red[2]+red[3];
}
__device__ __forceinline__ float block_max256(float v, float* red){
  #pragma unroll
  for(int o=32;o;o>>=1) v = fmaxf(v,__shfl_xor(v,o,64));
  __syncthreads();
  if((threadIdx.x&63)==0) red[threadIdx.x>>6]=v;
  __syncthreads();
  return fmaxf(fmaxf(red[0],red[1]),fmaxf(red[2],red[3]));
}

// ---------------- init: meannf=0, first_edge=E, cntb=0 --------------------
__global__ __launch_bounds__(256) void k_init(float* meannf, int* firstedge, int* cntb){
  int t = blockIdx.x*256+threadIdx.x;
  if(t < WB*WH) meannf[t]=0.f;
  if(t < WN) firstedge[t]=WE;
  if(t < WB) cntb[t]=0;
}

// ---------------- prep: wnT_hi/lo[n][k] = bf16 hi/lo of wn[k][n] ----------
__global__ __launch_bounds__(256) void k_prepw(const float* __restrict__ wn,
    unsigned short* __restrict__ th, unsigned short* __restrict__ tl){
  __shared__ float tile[64][68];
  int kt = blockIdx.x, nt = blockIdx.y, t = threadIdx.x;
  {
    int r = t>>2, q = t&3;
    const float4* src = (const float4*)(wn + (size_t)(kt*64 + r)*WH + nt*64 + q*16);
    float4 v0=src[0], v1=src[1], v2=src[2], v3=src[3];
    float* d = &tile[r][q*16];
    d[0]=v0.x; d[1]=v0.y; d[2]=v0.z; d[3]=v0.w;
    d[4]=v1.x; d[5]=v1.y; d[6]=v1.z; d[7]=v1.w;
    d[8]=v2.x; d[9]=v2.y; d[10]=v2.z; d[11]=v2.w;
    d[12]=v3.x; d[13]=v3.y; d[14]=v3.z; d[15]=v3.w;
  }
  __syncthreads();
  {
    int n = t>>2, q = t&3;
    #pragma unroll
    for(int e=0;e<16;++e){
      int kl = q*16 + e;
      float x = tile[kl][n];
      unsigned short h = f2bf(x);
      unsigned short l = f2bf(x - bf2f(h));
      size_t di = (size_t)(nt*64 + n)*WH + kt*64 + kl;
      th[di] = h; tl[di] = l;
    }
  }
}

// ---------------- 32-row GEMM, weights read once --------------------------
__device__ __forceinline__ void gemm32_body(
    const float* __restrict__ A, const float* __restrict__ W,
    const float* __restrict__ bias, float* __restrict__ C,
    int relu, const int* __restrict__ cntb, float* a_t){
  int t = threadIdx.x;
  for(int idx=t; idx<WH*32; idx+=256){
    int b = idx & 31, i = idx >> 5;
    float v = A[(size_t)b*WH + i];
    if(cntb){ int c = cntb[b]; v *= 1.f/(float)(c>1?c:1); }
    a_t[i*32 + b] = v;
  }
  __syncthreads();
  int jl = t & 63, bg = t >> 6;
  int j = blockIdx.x*64 + jl;
  float acc[8];
  #pragma unroll
  for(int k=0;k<8;++k) acc[k]=0.f;
  #pragma unroll 4
  for(int i=0;i<WH;++i){
    float w = W[(size_t)i*WH + j];
    const float4* ap = (const float4*)&a_t[i*32 + bg*8];
    float4 a0 = ap[0], a1 = ap[1];
    acc[0]+=a0.x*w; acc[1]+=a0.y*w; acc[2]+=a0.z*w; acc[3]+=a0.w*w;
    acc[4]+=a1.x*w; acc[5]+=a1.y*w; acc[6]+=a1.z*w; acc[7]+=a1.w*w;
  }
  float bj = bias? bias[j] : 0.f;
  #pragma unroll
  for(int bb=0;bb<8;++bb){
    float v = acc[bb] + bj;
    if(relu) v = fmaxf(v, 0.f);
    C[(size_t)(bg*8+bb)*WH + j] = v;
  }
}
__global__ __launch_bounds__(256) void k_gemm32(
    const float* __restrict__ A, const float* __restrict__ W,
    const float* __restrict__ bias, float* __restrict__ C,
    int relu, const int* __restrict__ cntb){
  __shared__ float a_t[WH*32];
  gemm32_body(A,W,bias,C,relu,cntb,a_t);
}
__global__ __launch_bounds__(256) void k_gemm32d(
    const float* __restrict__ A0, const float* __restrict__ W0,
    const float* __restrict__ b0, float* __restrict__ C0, int r0_, const int* c0,
    const float* __restrict__ A1, const float* __restrict__ W1,
    const float* __restrict__ b1, float* __restrict__ C1, int r1_, const int* c1){
  __shared__ float a_t[WH*32];
  if(blockIdx.y==0) gemm32_body(A0,W0,b0,C0,r0_,c0,a_t);
  else              gemm32_body(A1,W1,b1,C1,r1_,c1,a_t);
}

// ---------------- 32-row GEMM vs W^T: C[b][i]=sum_j A[b][j]*W[i][j] -------
__global__ __launch_bounds__(256) void k_gemm32t(
    const float* __restrict__ A, const float* __restrict__ W,
    float* __restrict__ C){
  __shared__ float a_t[WH*32];
  int t = threadIdx.x;
  for(int idx=t; idx<WH*32; idx+=256){
    int b = idx & 31, i = idx >> 5;
    a_t[i*32 + b] = A[(size_t)b*WH + i];
  }
  __syncthreads();
  int il = t & 63, bg = t >> 6;
  int i = blockIdx.x*64 + il;
  const float4* Wr = (const float4*)(W + (size_t)i*WH);
  float acc[8];
  #pragma unroll
  for(int k=0;k<8;++k) acc[k]=0.f;
  #pragma unroll 2
  for(int j4=0;j4<WH/4;++j4){
    float4 wv = Wr[j4];
    float ws[4] = {wv.x, wv.y, wv.z, wv.w};
    #pragma unroll
    for(int c=0;c<4;++c){
      const float4* ap = (const float4*)&a_t[(j4*4+c)*32 + bg*8];
      float4 a0 = ap[0], a1 = ap[1];
      float w = ws[c];
      acc[0]+=a0.x*w; acc[1]+=a0.y*w; acc[2]+=a0.z*w; acc[3]+=a0.w*w;
      acc[4]+=a1.x*w; acc[5]+=a1.y*w; acc[6]+=a1.z*w; acc[7]+=a1.w*w;
    }
  }
  #pragma unroll
  for(int bb=0;bb<8;++bb) C[(size_t)(bg*8+bb)*WH + i] = acc[bb];
}

// ---------------- qkT[b][h][i] = sum_d q[b,h*96+d]*ak_w[i,h*96+d] ---------
__global__ __launch_bounds__(256) void k_qkvec(const float* __restrict__ q,
    const float* __restrict__ akw, const float* __restrict__ akb,
    float* __restrict__ qkT, float* __restrict__ sconst){
  __shared__ float qlds[800];
  int b=blockIdx.y, ic=blockIdx.x, t=threadIdx.x;
  for(int idx=t; idx<WH; idx+=256){
    int h2 = idx/WDH, d = idx - h2*WDH;
    qlds[h2*100 + d] = q[(size_t)b*WH + idx];
  }
  __syncthreads();
  int il=t>>3, h=t&7;
  int i=ic*32+il;
  const float4* wr4 = (const float4*)(akw + (size_t)i*WH + h*WDH);
  float acc=0.f;
  #pragma unroll
  for(int u=0;u<WDH/4;++u){
    float4 w = wr4[u];
    float4 qv = *(const float4*)&qlds[h*100 + u*4];
    acc += w.x*qv.x + w.y*qv.y + w.z*qv.z + w.w*qv.w;
  }
  qkT[((size_t)b*WHEADS+h)*WH + i] = acc;
  if(ic==0 && il==0){
    float sc=0.f;
    for(int d=0;d<WDH;++d) sc += qlds[h*100+d]*akb[h*WDH+d];
    sconst[b*WHEADS+h]=sc;
  }
}

// ---------------- numer_const[b]=qp2.bn ; qn[b]=max(||qp2||,1e-8) ---------
__global__ __launch_bounds__(256) void k_qmisc(const float* __restrict__ qp2,
    const float* __restrict__ pbn, float* __restrict__ nconst, float* __restrict__ qn){
  __shared__ float red[4];
  int b=blockIdx.x, t=threadIdx.x;
  float s1=0.f,s2=0.f;
  for(int i=t;i<WH;i+=256){ float v=qp2[(size_t)b*WH+i]; s1+=v*pbn[i]; s2+=v*v; }
  s1=block_sum256(s1,red);
  s2=block_sum256(s2,red);
  if(t==0){ nconst[b]=s1; qn[b]=fmaxf(sqrtf(s2),1e-8f); }
}

// ---------------- MFMA bf16 hi/lo: nn[n]=||nf@wn+bn|| ---------------------
// 128x256 tile, K-step 32, LDS 48KB -> 2 blocks/CU. 8 waves (2x4), wave 64x64.
__global__ __launch_bounds__(512) void k_normM(
    const float* __restrict__ nf, const uint4* __restrict__ wnTh,
    const uint4* __restrict__ wnTl, const float* __restrict__ bn,
    float* __restrict__ nnout){
  __shared__ uint4 Ah[128*4], Al[128*4];   // 8 KB each
  __shared__ uint4 Bh[256*4], Bl[256*4];   // 16 KB each
  __shared__ float sqred[128];
  int t = threadIdx.x, lane = t & 63, wid = t >> 6;
  int wr = wid >> 2, wc = wid & 3;
  int l15 = lane & 15, lg = lane >> 4;
  int r0 = blockIdx.x * 128;
  if(t < 128) sqred[t] = 0.f;
  float sqr[4][4];
  #pragma unroll
  for(int mi=0;mi<4;++mi)
    #pragma unroll
    for(int r=0;r<4;++r) sqr[mi][r]=0.f;

  int sa_r = t >> 2, sa_q = t & 3;
  int sb_n = t >> 1, sb_h = t & 1;

  for(int ct=0; ct<3; ++ct){
    f32x4 acc[4][4];
    #pragma unroll
    for(int mi=0;mi<4;++mi)
      #pragma unroll
      for(int ni=0;ni<4;++ni) acc[mi][ni] = (f32x4){0.f,0.f,0.f,0.f};

    for(int kt=0; kt<24; ++kt){
      __syncthreads();
      { // stage A: rows r0..+128, k = kt*32..+32 (8 k-elems per thread)
        const float4* src = (const float4*)(nf + (size_t)(r0 + sa_r)*WH + kt*32 + sa_q*8);
        float4 v0=src[0], v1=src[1];
        float vals[8] = {v0.x,v0.y,v0.z,v0.w, v1.x,v1.y,v1.z,v1.w};
        unsigned int hd[4], ld_[4];
        #pragma unroll
        for(int e=0;e<4;++e){
          float x0 = vals[2*e], x1 = vals[2*e+1];
          unsigned short h0 = f2bf(x0), h1 = f2bf(x1);
          unsigned short l0 = f2bf(x0 - bf2f(h0)), l1 = f2bf(x1 - bf2f(h1));
          hd[e] = (unsigned)h0 | ((unsigned)h1 << 16);
          ld_[e] = (unsigned)l0 | ((unsigned)l1 << 16);
        }
        int sw = sa_r & 3;
        uint4 uh; uh.x=hd[0]; uh.y=hd[1]; uh.z=hd[2]; uh.w=hd[3];
        uint4 ul; ul.x=ld_[0]; ul.y=ld_[1]; ul.z=ld_[2]; ul.w=ld_[3];
        Ah[sa_r*4 + (sa_q ^ sw)] = uh;
        Al[sa_r*4 + (sa_q ^ sw)] = ul;
      }
      { // stage B: n = ct*256..+256, k = kt*32..+32 (16 bf16 = 2 uint4/thread)
        size_t gi = (size_t)(ct*256 + sb_n)*96 + kt*4 + sb_h*2;
        int sw = sb_n & 3;
        uint4 b0 = wnTh[gi], b1 = wnTh[gi+1];
        Bh[sb_n*4 + ((2*sb_h  ) ^ sw)] = b0;
        Bh[sb_n*4 + ((2*sb_h+1) ^ sw)] = b1;
        uint4 c0 = wnTl[gi], c1 = wnTl[gi+1];
        Bl[sb_n*4 + ((2*sb_h  ) ^ sw)] = c0;
        Bl[sb_n*4 + ((2*sb_h+1) ^ sw)] = c1;
      }
      __syncthreads();
      bf16x8 ah[4], al_[4], bh[4], bl_[4];
      #pragma unroll
      for(int mi=0;mi<4;++mi){
        int row = wr*64 + mi*16 + l15;
        int u = lg ^ (row & 3);
        ah[mi]  = ((const bf16x8*)Ah)[row*4 + u];
        al_[mi] = ((const bf16x8*)Al)[row*4 + u];
      }
      #pragma unroll
      for(int ni=0;ni<4;++ni){
        int row = wc*64 + ni*16 + l15;
        int u = lg ^ (row & 3);
        bh[ni]  = ((const bf16x8*)Bh)[row*4 + u];
        bl_[ni] = ((const bf16x8*)Bl)[row*4 + u];
      }
      __builtin_amdgcn_s_setprio(1);
      #pragma unroll
      for(int mi=0;mi<4;++mi)
        #pragma unroll
        for(int ni=0;ni<4;++ni){
          acc[mi][ni] = __builtin_amdgcn_mfma_f32_16x16x32_bf16(ah[mi],  bh[ni],  acc[mi][ni], 0,0,0);
          acc[mi][ni] = __builtin_amdgcn_mfma_f32_16x16x32_bf16(ah[mi],  bl_[ni], acc[mi][ni], 0,0,0);
          acc[mi][ni] = __builtin_amdgcn_mfma_f32_16x16x32_bf16(al_[mi], bh[ni],  acc[mi][ni], 0,0,0);
        }
      __builtin_amdgcn_s_setprio(0);
    }
    #pragma unroll
    for(int ni=0;ni<4;++ni){
      int col = ct*256 + wc*64 + ni*16 + l15;
      float bj = bn[col];
      #pragma unroll
      for(int mi=0;mi<4;++mi)
        #pragma unroll
        for(int r=0;r<4;++r){
          float v = acc[mi][ni][r] + bj;
          sqr[mi][r] += v*v;
        }
    }
  }
  #pragma unroll
  for(int mi=0;mi<4;++mi)
    #pragma unroll
    for(int r=0;r<4;++r){
      float v = sqr[mi][r];
      v += __shfl_xor(v, 1, 64);
      v += __shfl_xor(v, 2, 64);
      v += __shfl_xor(v, 4, 64);
      v += __shfl_xor(v, 8, 64);
      sqr[mi][r] = v;
    }
  if(l15 == 0){
    #pragma unroll
    for(int mi=0;mi<4;++mi)
      #pragma unroll
      for(int r=0;r<4;++r){
        int row = wr*64 + mi*16 + lg*4 + r;
        atomicAdd(&sqred[row], sqr[mi][r]);
      }
  }
  __syncthreads();
  if(t < 128) nnout[r0 + t] = fmaxf(sqrtf(sqred[t]), 1e-8f);
}

// ---------------- node pass 1: scores, numer, per-batch nf sums -----------
// qkT layout [b][h][i] -> all loads lane-coalesced; b = n>>11.
__global__ __launch_bounds__(256) void k_node1(
    const float* __restrict__ nf,
    const float* __restrict__ qkT, const float* __restrict__ wq2,
    const float* __restrict__ sconst, const float* __restrict__ nconst,
    float* __restrict__ s_out, float* __restrict__ numer,
    float* __restrict__ meannf, int* __restrict__ cntb){
  __shared__ float m_lds[4][WH];
  int lane = threadIdx.x&63, w = threadIdx.x>>6;
  int n0 = blockIdx.x*64;
  int b = n0 >> 11;
  const float4* qkb4 = (const float4*)(qkT + (size_t)b*WHEADS*WH);
  const float4* wqb4 = (const float4*)(wq2 + (size_t)b*WH);
  float sc[8];
  #pragma unroll
  for(int h=0;h<8;++h) sc[h]=sconst[b*WHEADS+h];
  float ncst = nconst[b];
  float macc[12];
  #pragma unroll
  for(int i=0;i<12;++i) macc[i]=0.f;
  for(int q_=0;q_<16;++q_){
    int n = n0 + w*16 + q_;
    const float4* nfr = (const float4*)(nf + (size_t)n*WH);
    float acc[8]; float anu=0.f;
    #pragma unroll
    for(int h=0;h<8;++h) acc[h]=0.f;
    #pragma unroll
    for(int tt=0;tt<3;++tt){
      int i4 = lane + 64*tt;
      float4 xv = nfr[i4];
      float4 wv = wqb4[i4];
      #pragma unroll
      for(int h=0;h<8;++h){
        float4 qv = qkb4[h*192 + i4];
        acc[h] += xv.x*qv.x + xv.y*qv.y + xv.z*qv.z + xv.w*qv.w;
      }
      anu += xv.x*wv.x + xv.y*wv.y + xv.z*wv.z + xv.w*wv.w;
      macc[tt*4+0]+=xv.x; macc[tt*4+1]+=xv.y; macc[tt*4+2]+=xv.z; macc[tt*4+3]+=xv.w;
    }
    #pragma unroll
    for(int h=0;h<8;++h) acc[h]=wave_sum64(acc[h]);
    anu = wave_sum64(anu);
    if(lane==0){
      #pragma unroll
      for(int h=0;h<8;++h) s_out[(size_t)n*8+h] = SCALE_QK*(acc[h]+sc[h]);
      numer[n] = anu + ncst;
    }
  }
  #pragma unroll
  for(int tt=0;tt<3;++tt){
    #pragma unroll
    for(int u=0;u<4;++u) m_lds[w][4*lane+256*tt+u]=macc[tt*4+u];
  }
  __syncthreads();
  for(int i=threadIdx.x;i<WH;i+=256)
    atomicAdd(&meannf[(size_t)b*WH+i],
              m_lds[0][i]+m_lds[1][i]+m_lds[2][i]+m_lds[3][i]);
  if(threadIdx.x==0) atomicAdd(&cntb[b],64);
}

// ---------------- softmax stats per (b,h) ---------------------------------
__global__ __launch_bounds__(256) void k_stats(const float* __restrict__ s,
    float* __restrict__ rowmax, float* __restrict__ rowinv){
  __shared__ float red[4];
  int b = blockIdx.x>>3, h = blockIdx.x&7;
  const float* sp = s + (size_t)b*WNPB*8 + h;
  float mx=-3e38f;
  for(int i=threadIdx.x;i<WNPB;i+=256) mx=fmaxf(mx, sp[(size_t)i*8]);
  mx = block_max256(mx, red);
  float se=0.f;
  for(int i=threadIdx.x;i<WNPB;i+=256) se += __expf(sp[(size_t)i*8]-mx);
  se = block_sum256(se, red);
  if(threadIdx.x==0){ rowmax[blockIdx.x]=mx; rowinv[blockIdx.x]=1.f/se; }
}

// ---------------- node pass 2: wnf[b,h,ds] = sum_n p[n,h]*nf[n,ds] --------
// block (ds, b): owns disjoint 64-col slice of all 8 heads. No atomics.
__global__ __launch_bounds__(256) void k_node2(
    const float* __restrict__ nf, const float* __restrict__ s,
    const float* __restrict__ rowmax, const float* __restrict__ rowinv,
    float* __restrict__ wnf){
  __shared__ float p_lds[WNPB*8];  // 64 KB
  int b = blockIdx.y, ds = blockIdx.x;
  int t = threadIdx.x;
  float rm[8], ri[8];
  #pragma unroll
  for(int h=0;h<8;++h){ rm[h]=rowmax[b*8+h]; ri[h]=rowinv[b*8+h]; }
  for(int idx=t; idx<WNPB*8; idx+=256){
    int nl = idx>>3, h = idx&7;
    p_lds[idx] = __expf(s[((size_t)b*WNPB+nl)*8+h] - rm[h]) * ri[h];
  }
  __syncthreads();
  int cg = t & 15, ng = t >> 4;
  const float* nfb = nf + (size_t)b*WNPB*WH + ds*64 + cg*4;
  f32x4 acc8[8];
  #pragma unroll
  for(int h=0;h<8;++h) acc8[h]=(f32x4){0.f,0.f,0.f,0.f};
  for(int m=ng; m<WNPB; m+=16){
    float4 x = *(const float4*)(nfb + (size_t)m*WH);
    const float* pm = &p_lds[m*8];
    #pragma unroll
    for(int h=0;h<8;++h){
      float p = pm[h];
      acc8[h][0] += p*x.x; acc8[h][1] += p*x.y;
      acc8[h][2] += p*x.z; acc8[h][3] += p*x.w;
    }
  }
  __syncthreads();
  f32x4* red4 = (f32x4*)p_lds;
  #pragma unroll
  for(int h=0;h<8;++h) red4[(ng*16+cg)*8 + h] = acc8[h];
  __syncthreads();
  if(t < 128){
    int cg2 = t&15, h2 = t>>4;
    f32x4 sum = (f32x4){0.f,0.f,0.f,0.f};
    #pragma unroll
    for(int g=0;g<16;++g){ f32x4 v = red4[(g*16+cg2)*8+h2];
      sum[0]+=v[0]; sum[1]+=v[1]; sum[2]+=v[2]; sum[3]+=v[3]; }
    float* dst = wnf + ((size_t)b*WHEADS+h2)*WH + ds*64 + cg2*4;
    dst[0]=sum[0]; dst[1]=sum[1]; dst[2]=sum[2]; dst[3]=sum[3];
  }
}

// ---------------- ctx: head-structured 32-row GEMM ------------------------
__global__ __launch_bounds__(256) void k_ctx(const float* __restrict__ wnf,
    const float* __restrict__ W, const float* __restrict__ bias,
    float* __restrict__ C){
  __shared__ float a_lds[WHEADS*WH];
  int b = blockIdx.x, t = threadIdx.x;
  const float* Ar = wnf + (size_t)b*WHEADS*WH;
  for(int i=t;i<WHEADS*WH;i+=256) a_lds[i]=Ar[i];
  __syncthreads();
  #pragma unroll
  for(int jo=0;jo<3;++jo){
    int j = jo*256+t;
    const float* ap = a_lds + (j/WDH)*WH;
    const float* wp = W + j;
    float acc=0.f;
    #pragma unroll 4
    for(int i=0;i<WH;++i) acc += ap[i]*wp[(size_t)i*WH];
    C[(size_t)b*WH+j] = acc + bias[j];
  }
}

// ---------------- top3 + path features fused ------------------------------
__device__ __forceinline__ void top3_insert(float v, int i, float* tv, int* ti){
  if (v>tv[0] || (v==tv[0] && i<ti[0])){
    tv[2]=tv[1]; ti[2]=ti[1]; tv[1]=tv[0]; ti[1]=ti[0]; tv[0]=v; ti[0]=i;
  } else if (v>tv[1] || (v==tv[1] && i<ti[1])){
    tv[2]=tv[1]; ti[2]=ti[1]; tv[1]=v; ti[1]=i;
  } else if (v>tv[2] || (v==tv[2] && i<ti[2])){
    tv[2]=v; ti[2]=i;
  }
}
__global__ __launch_bounds__(256) void k_tp(const float* __restrict__ numer,
    const float* __restrict__ nrm, const float* __restrict__ qn,
    const int* __restrict__ firstedge, const int* __restrict__ dst,
    const float* __restrict__ nf, float* __restrict__ mpaths,
    int* __restrict__ cntpath){
  __shared__ float sv[256][3];
  __shared__ int   si[256][3];
  int b=blockIdx.x, t=threadIdx.x;
  float qv = qn[b];
  float tv[3]={-3e38f,-3e38f,-3e38f};
  int   ti[3]={0x7fffffff,0x7fffffff,0x7fffffff};
  for(int u=t;u<WNPB;u+=256){
    int n=b*WNPB+u;
    float v = numer[n]/(qv*nrm[n]);
    top3_insert(v,n,tv,ti);
  }
  sv[t][0]=tv[0];sv[t][1]=tv[1];sv[t][2]=tv[2];
  si[t][0]=ti[0];si[t][1]=ti[1];si[t][2]=ti[2];
  __syncthreads();
  for(int st=128;st;st>>=1){
    if(t<st){
      #pragma unroll
      for(int k=0;k<3;++k) top3_insert(sv[t+st][k], si[t+st][k], tv, ti);
      sv[t][0]=tv[0];sv[t][1]=tv[1];sv[t][2]=tv[2];
      si[t][0]=ti[0];si[t][1]=ti[1];si[t][2]=ti[2];
    }
    __syncthreads();
  }
  // path features
  int sl[3], nl[3], vl[3]; int cnt=0;
  #pragma unroll
  for(int k=0;k<3;++k){
    int st = si[0][k];
    int fe = firstedge[st];
    int valid = fe<WE;
    sl[k]=st; nl[k]= valid? dst[fe] : 0; vl[k]=valid; cnt+=valid;
  }
  float inv = 1.f/(float)(cnt>1?cnt:1);
  for(int j=t;j<WH;j+=256){
    float acc=0.f;
    #pragma unroll
    for(int k=0;k<3;++k)
      if(vl[k]) acc += 0.5f*(nf[(size_t)sl[k]*WH+j] + nf[(size_t)nl[k]*WH+j]);
    mpaths[(size_t)b*WH+j]=acc*inv;
  }
  if(t==0) cntpath[b]=cnt;
}

// ---------------- edge scan (bidx[n] == n>>11) + zero fuse acc ------------
__global__ __launch_bounds__(256) void k_edges(const int* __restrict__ ei,
    int* __restrict__ firstedge, float* __restrict__ fzero){
  int e = blockIdx.x*256+threadIdx.x;
  if(e < 2*WB*WH) fzero[e] = 0.f;
  if(e<WE){
    int s=ei[e], d=ei[WE+e];
    if((s>>11)==(d>>11)) atomicMin(&firstedge[s], e);
  }
}

// ---------------- select + LayerNorm (cntpath nullable) -------------------
__global__ __launch_bounds__(256) void k_selln(const float* __restrict__ agg,
    const float* __restrict__ bmean, const int* __restrict__ cntpath,
    const float* __restrict__ g, const float* __restrict__ bb,
    float* __restrict__ out){
  __shared__ float red[4];
  int b=blockIdx.x, t=threadIdx.x;
  const float* src = agg;
  if(cntpath && cntpath[b]<=0) src = bmean;
  src += (size_t)b*WH;
  float x[3];
  #pragma unroll
  for(int jo=0;jo<3;++jo) x[jo]=src[jo*256+t];
  float s = block_sum256(x[0]+x[1]+x[2], red);
  float m = s*(1.f/768.f);
  float d0=x[0]-m,d1=x[1]-m,d2=x[2]-m;
  float v = block_sum256(d0*d0+d1*d1+d2*d2, red)*(1.f/768.f);
  float inv = rsqrtf(v+1e-5f);
  #pragma unroll
  for(int jo=0;jo<3;++jo){ int j=jo*256+t;
    out[(size_t)b*WH+j]=(x[jo]-m)*inv*g[j]+bb[j]; }
}

// ---------------- fusion matmuls: weights read once, K-chunked ------------
__global__ __launch_bounds__(256) void k_fuse_mm(
    const float* __restrict__ query, const float* __restrict__ graphr,
    const float* __restrict__ pathr, const float* __restrict__ gw,
    const float* __restrict__ pw, float* __restrict__ facc){
  __shared__ float c_t[576*32];
  int t = threadIdx.x;
  int jt = blockIdx.x, kc = blockIdx.y;
  for(int idx=t; idx<576*32; idx+=256){
    int b = idx & 31, ii = idx >> 5;
    int gi = kc*576 + ii;
    float v;
    if(gi < WH)        v = query [(size_t)b*WH + gi];
    else if(gi < 2*WH) v = graphr[(size_t)b*WH + gi - WH];
    else               v = pathr [(size_t)b*WH + gi - 2*WH];
    c_t[ii*32 + b] = v;
  }
  __syncthreads();
  int jl = t & 63, bg = t >> 6;
  int j = jt*64 + jl;
  float ag[8], ap[8];
  #pragma unroll
  for(int k=0;k<8;++k){ ag[k]=0.f; ap[k]=0.f; }
  #pragma unroll 2
  for(int ii=0;ii<576;++ii){
    size_t wi = (size_t)(kc*576 + ii)*WH + j;
    float wg = gw[wi], wp = pw[wi];
    const float4* cp = (const float4*)&c_t[ii*32 + bg*8];
    float4 a0 = cp[0], a1 = cp[1];
    ag[0]+=a0.x*wg; ag[1]+=a0.y*wg; ag[2]+=a0.z*wg; ag[3]+=a0.w*wg;
    ag[4]+=a1.x*wg; ag[5]+=a1.y*wg; ag[6]+=a1.z*wg; ag[7]+=a1.w*wg;
    ap[0]+=a0.x*wp; ap[1]+=a0.y*wp; ap[2]+=a0.z*wp; ap[3]+=a0.w*wp;
    ap[4]+=a1.x*wp; ap[5]+=a1.y*wp; ap[6]+=a1.z*wp; ap[7]+=a1.w*wp;
  }
  #pragma unroll
  for(int bb=0;bb<8;++bb){
    atomicAdd(&facc[(size_t)(bg*8+bb)*WH + j], ag[bb]);
    atomicAdd(&facc[(size_t)WB*WH + (size_t)(bg*8+bb)*WH + j], ap[bb]);
  }
}

// ---------------- fusion epilogue ----------------------------------------
__global__ __launch_bounds__(256) void k_fuse_ep(const float* __restrict__ facc,
    const float* __restrict__ gb, const float* __restrict__ pb,
    const float* __restrict__ g, const float* __restrict__ bb,
    float* __restrict__ out){
  __shared__ float red[4];
  int b=blockIdx.x, t=threadIdx.x;
  float vals[3];
  #pragma unroll
  for(int jo=0;jo<3;++jo){
    int j=jo*256+t;
    float ag = facc[(size_t)b*WH + j] + gb[j];
    float ap = facc[(size_t)WB*WH + (size_t)b*WH + j] + pb[j];
    float sg = 1.f/(1.f+__expf(-ag));
    vals[jo]=sg*ap;
  }
  float s = block_sum256(vals[0]+vals[1]+vals[2], red);
  float m = s*(1.f/768.f);
  float d0=vals[0]-m,d1=vals[1]-m,d2=vals[2]-m;
  float v = block_sum256(d0*d0+d1*d1+d2*d2, red)*(1.f/768.f);
  float inv = rsqrtf(v+1e-5f);
  #pragma unroll
  for(int jo=0;jo<3;++jo){
    int j=jo*256+t;
    out[(size_t)b*WH+j] = (vals[jo]-m)*inv*g[j]+bb[j];
  }
}

extern "C" void kernel_launch(void* const* d_in, const int* in_sizes, int n_in,
                              void* d_out, int out_size, void* d_ws, size_t ws_size,
                              hipStream_t stream){
  const float* query  =(const float*)d_in[0];
  const float* nf     =(const float*)d_in[1];
  const int*   ei     =(const int*)  d_in[2];
  const float* gr_wq  =(const float*)d_in[4];
  const float* gr_bq  =(const float*)d_in[5];
  const float* gr_aq_w=(const float*)d_in[6];
  const float* gr_aq_b=(const float*)d_in[7];
  const float* gr_ak_w=(const float*)d_in[8];
  const float* gr_ak_b=(const float*)d_in[9];
  const float* gr_av_w=(const float*)d_in[10];
  const float* gr_av_b=(const float*)d_in[11];
  const float* gr_ao_w=(const float*)d_in[12];
  const float* gr_ao_b=(const float*)d_in[13];
  const float* gr_ln_g=(const float*)d_in[14];
  const float* gr_ln_b=(const float*)d_in[15];
  const float* pf_wq  =(const float*)d_in[16];
  const float* pf_bq  =(const float*)d_in[17];
  const float* pf_wn  =(const float*)d_in[18];
  const float* pf_bn  =(const float*)d_in[19];
  const float* pf_a1_w=(const float*)d_in[20];
  const float* pf_a1_b=(const float*)d_in[21];
  const float* pf_a2_w=(const float*)d_in[22];
  const float* pf_a2_b=(const float*)d_in[23];
  const float* pf_ln_g=(const float*)d_in[24];
  const float* pf_ln_b=(const float*)d_in[25];
  const float* fu_gw  =(const float*)d_in[26];
  const float* fu_gb  =(const float*)d_in[27];
  const float* fu_pw  =(const float*)d_in[28];
  const float* fu_pb  =(const float*)d_in[29];
  const float* fu_ln_g=(const float*)d_in[30];
  const float* fu_ln_b=(const float*)d_in[31];
  float* out =(float*)d_out;

  float* w=(float*)d_ws;
  size_t o=0;
  float* sregion=w+o; o+=(size_t)WN*WHEADS + WN;   // s + numer; overlaid w/ wnT
  float* s      = sregion;
  float* numer  = sregion + (size_t)WN*WHEADS;
  unsigned short* wnTh = (unsigned short*)sregion;
  unsigned short* wnTl = ((unsigned short*)sregion) + (size_t)WH*WH;
  float* qp     =w+o; o+=WB*WH;
  float* qp2    =w+o; o+=WB*WH;
  float* q      =w+o; o+=WB*WH;
  float* wq2    =w+o; o+=WB*WH;
  float* qkvecT =w+o; o+=(size_t)WB*WH*WHEADS;     // overlaid: ctxo + fuse_acc
  float* ctxo   = qkvecT;
  float* fuse_acc = qkvecT + WB*WH;
  float* sconst =w+o; o+=WB*WHEADS;
  float* nconst =w+o; o+=64;
  float* qn     =w+o; o+=64;
  float* nrm    =w+o; o+=WN;
  float* meannf =w+o; o+=WB*WH;
  float* rowmax =w+o; o+=WB*WHEADS;
  float* rowinv =w+o; o+=WB*WHEADS;
  float* wnf    =w+o; o+=(size_t)WB*WHEADS*WH;
  float* ctx    =w+o; o+=WB*WH;
  float* graphr =w+o; o+=WB*WH;
  float* mpaths =w+o; o+=WB*WH;
  float* t1     =w+o; o+=WB*WH;
  float* agg    =w+o; o+=WB*WH;
  float* bmean  =w+o; o+=WB*WH;
  float* pathr  =w+o; o+=WB*WH;
  int* iw=(int*)(w+o);
  int* firstedge=iw; iw+=WN;
  int* cntb     =iw; iw+=64;
  int* cntpath  =iw; iw+=64;

  dim3 blk(256);
  k_init   <<<256,blk,0,stream>>>(meannf, firstedge, cntb);
  k_prepw  <<<dim3(12,12),blk,0,stream>>>(pf_wn, wnTh, wnTl);
  k_gemm32d<<<dim3(12,2),blk,0,stream>>>(query, gr_wq, gr_bq, qp, 0, nullptr,
                                         query, pf_wq, pf_bq, qp2, 0, nullptr);
  k_gemm32 <<<12,blk,0,stream>>>(qp, gr_aq_w, gr_aq_b, q, 0, nullptr);
  k_gemm32t<<<12,blk,0,stream>>>(qp2, pf_wn, wq2);
  k_qkvec  <<<dim3(24,32),blk,0,stream>>>(q, gr_ak_w, gr_ak_b, qkvecT, sconst);
  k_qmisc  <<<WB,blk,0,stream>>>(qp2, pf_bn, nconst, qn);
  k_normM  <<<WN/128,dim3(512),0,stream>>>(nf, (const uint4*)wnTh, (const uint4*)wnTl, pf_bn, nrm);
  k_node1  <<<WN/64,blk,0,stream>>>(nf, qkvecT, wq2, sconst, nconst, s, numer, meannf, cntb);
  k_stats  <<<WB*WHEADS,blk,0,stream>>>(s, rowmax, rowinv);
  k_node2  <<<dim3(12,WB),blk,0,stream>>>(nf, s, rowmax, rowinv, wnf);
  k_ctx    <<<WB,blk,0,stream>>>(wnf, gr_av_w, gr_av_b, ctx);
  k_gemm32 <<<12,blk,0,stream>>>(ctx, gr_ao_w, gr_ao_b, ctxo, 0, nullptr);
  k_selln  <<<WB,blk,0,stream>>>(ctxo, ctxo, nullptr, gr_ln_g, gr_ln_b, graphr);
  k_edges  <<<WE/256,blk,0,stream>>>(ei, firstedge, fuse_acc);
  k_tp     <<<WB,blk,0,stream>>>(numer, nrm, qn, firstedge, ei+WE, nf, mpaths, cntpath);
  k_gemm32d<<<dim3(12,2),blk,0,stream>>>(mpaths, pf_a1_w, pf_a1_b, t1, 1, nullptr,
                                         meannf, pf_wn, pf_bn, bmean, 0, cntb);
  k_gemm32 <<<12,blk,0,stream>>>(t1, pf_a2_w, pf_a2_b, agg, 0, nullptr);
  k_selln  <<<WB,blk,0,stream>>>(agg, bmean, cntpath, pf_ln_g, pf_ln_b, pathr);
  k_fuse_mm<<<dim3(12,4),blk,0,stream>>>(query, graphr, pathr, fu_gw, fu_pw, fuse_acc);
  k_fuse_ep<<<WB,blk,0,stream>>>(fuse_acc, fu_gb, fu_pb, fu_ln_g, fu_ln_b, out);
}